// Round 9
// baseline (531.735 us; speedup 1.0000x reference)
//
#include <hip/hip_runtime.h>
#include <math.h>

#define NN 50000
#define NE 600000
#define NG 512

typedef unsigned int u32;
typedef unsigned short u16;

typedef __attribute__((ext_vector_type(8))) short bf16x8;
typedef __attribute__((ext_vector_type(4))) float f32x4;
typedef __attribute__((ext_vector_type(4))) unsigned int u32x4;

__device__ __forceinline__ float bf2f(u16 u) {
  return __uint_as_float(((u32)u) << 16);
}
__device__ __forceinline__ u16 f2bf(float f) {
  u32 u = __float_as_uint(f);
  u32 lsb = (u >> 16) & 1u;
  u += 0x7fffu + lsb;          // RNE
  return (u16)(u >> 16);
}

// ---- graph-capture-safe grid barrier: one-shot counter (zeroed by memset each replay) ----
__device__ __forceinline__ void gridbar(int* bar, int nblk) {
  __syncthreads();
  if (threadIdx.x == 0) {
    __threadfence();                 // release: make this block's stores visible
    atomicAdd(bar, 1);
    while (atomicAdd(bar, 0) < nblk) __builtin_amdgcn_s_sleep(8);
    __threadfence();                 // acquire: see other blocks' stores
  }
  __syncthreads();
}

// ================= fused prep: cast x, count degrees, cast+transpose weights ========
// blocks [0,12500): cast x->xb ; [12500,14844): deg_count ;
// [14844,14972): castW0 (swz) ; [14972,15100): castW1 (swz) ;
// [15100,15132): WlT2 (swz) ; [15132,15164): WrT2 (swz)
__global__ __launch_bounds__(256)
void prep_k(const float* __restrict__ x, u32* __restrict__ xb,
            const int* __restrict__ ei, int* __restrict__ deg,
            const float* __restrict__ Wl0, const float* __restrict__ Wr0, u16* __restrict__ WbT0,
            const float* __restrict__ Wl1, const float* __restrict__ Wr1, u16* __restrict__ WbT1,
            const float* __restrict__ Wl2, u16* __restrict__ WlT2,
            const float* __restrict__ Wr2, u16* __restrict__ WrT2) {
  int b = blockIdx.x;
  int tid = threadIdx.x;
  if (b < 12500) {
    int t = b * 256 + tid;                       // 3,200,000 exactly
    float2 v = ((const float2*)x)[t];
    xb[t] = (u32)f2bf(v.x) | ((u32)f2bf(v.y) << 16);
  } else if (b < 14844) {
    int e = (b - 12500) * 256 + tid;
    if (e < NE) atomicAdd(&deg[ei[NE + e]], 1);
  } else if (b < 15100) {
    // K=256 weight cast+transpose, pre-swizzled: WbT[n][k], 16B chunk idx ^= (n&7)
    bool w1 = (b >= 14972);
    int t = (b - (w1 ? 14972 : 14844)) * 256 + tid;   // 128*256
    int n = t >> 8;
    int k = t & 255;
    const float* Wl = w1 ? Wl1 : Wl0;
    const float* Wr = w1 ? Wr1 : Wr0;
    float v = (k < 128) ? Wl[k * 128 + n] : Wr[(k - 128) * 128 + n];
    int c = k >> 3, e = k & 7;
    u16* dst = w1 ? WbT1 : WbT0;
    dst[n * 256 + (((c ^ (n & 7)) << 3) | e)] = f2bf(v);
  } else {
    // K=128 -> 64 cols, pre-swizzled
    bool wr = (b >= 15132);
    int t = (b - (wr ? 15132 : 15100)) * 256 + tid;   // 8192 = 64*128
    int n = t >> 7;
    int k = t & 127;
    const float* W = wr ? Wr2 : Wl2;
    float v = W[k * 64 + n];
    int c = k >> 3, e = k & 7;
    u16* dst = wr ? WrT2 : WlT2;
    dst[n * 128 + (((c ^ (n & 7)) << 3) | e)] = f2bf(v);
  }
}

// ================= merged CSR: scan1 -> bar -> prefix+scan3 -> bar -> fill ========
// 196 blocks x 256 thr (trivially co-resident; spin barrier safe).
__global__ __launch_bounds__(256)
void csr_k(const int* __restrict__ ei, const int* __restrict__ deg,
           int* __restrict__ bsum, int* __restrict__ row_ptr,
           int* __restrict__ cursor, int* __restrict__ perm, int* __restrict__ bars) {
  __shared__ int s[256];
  int t = threadIdx.x;
  int b = blockIdx.x;
  int idx = b * 256 + t;
  int v = (idx < NN) ? deg[idx] : 0;

  // ---- tile sums ----
  s[t] = v;
  __syncthreads();
  for (int off = 128; off > 0; off >>= 1) {
    if (t < off) s[t] += s[t + off];
    __syncthreads();
  }
  if (t == 0) bsum[b] = s[0];
  gridbar(&bars[0], 196);

  // ---- tile offset = sum bsum[0..b-1] ----
  s[t] = (t < b) ? bsum[t] : 0;      // t < b <= 195 -> in bounds
  __syncthreads();
  for (int off = 128; off > 0; off >>= 1) {
    if (t < off) s[t] += s[t + off];
    __syncthreads();
  }
  int bofs_b = s[0];
  __syncthreads();

  // ---- in-tile inclusive scan -> row_ptr / cursor ----
  s[t] = v;
  __syncthreads();
  for (int off = 1; off < 256; off <<= 1) {
    int add = (t >= off) ? s[t - off] : 0;
    __syncthreads();
    s[t] += add;
    __syncthreads();
  }
  if (idx < NN) {
    int p = bofs_b + s[t] - v;
    row_ptr[idx] = p;
    cursor[idx] = p;
  }
  if (b == 0 && t == 0) row_ptr[NN] = NE;
  gridbar(&bars[1], 196);

  // ---- fill perm (grid-stride over edges) ----
  for (int e = b * 256 + t; e < NE; e += 196 * 256) {
    int pos = atomicAdd(&cursor[ei[NE + e]], 1);
    perm[pos] = ei[e];
  }
}

// ===== gather-mean (128 ch): 4 nodes/wave, batch-8 dwordx4 (8 KB in flight) =====
__global__ __launch_bounds__(256)
void gather4_k(const u16* __restrict__ xb, const int* __restrict__ row_ptr,
               const int* __restrict__ perm, u16* __restrict__ aggb) {
  int wave = threadIdx.x >> 6;
  int lane = threadIdx.x & 63;
  int grp  = lane >> 4;
  int l16  = lane & 15;
  int n = (blockIdx.x * 4 + wave) * 4 + grp;     // 3125*4*4 = 50000
  int beg = row_ptr[n];
  int cnt = row_ptr[n + 1] - beg;
  int beg_s = min(beg, NE - 1);                  // safe base for clamped reads
  int last = max(cnt - 1, 0);
  int m = max(cnt, __shfl_xor(cnt, 16));
  int jmax = max(m, __shfl_xor(m, 32));          // wave-uniform loop bound
  float acc[8];
#pragma unroll
  for (int i = 0; i < 8; i++) acc[i] = 0.f;
  const u32x4* xv = (const u32x4*)xb;            // row = 16 chunks of 16 B
  for (int base = 0; base < jmax; base += 8) {
    int idx[8];
#pragma unroll
    for (int j = 0; j < 8; j++) idx[j] = perm[beg_s + min(base + j, last)];
    u32x4 v[8];
#pragma unroll
    for (int j = 0; j < 8; j++) v[j] = xv[(size_t)idx[j] * 16 + l16];
#pragma unroll
    for (int j = 0; j < 8; j++) {
      bool live = (base + j) < cnt;
#pragma unroll
      for (int w = 0; w < 4; w++) {
        u32 u = v[j][w];
        acc[2 * w]     += live ? __uint_as_float(u << 16) : 0.f;
        acc[2 * w + 1] += live ? __uint_as_float(u & 0xffff0000u) : 0.f;
      }
    }
  }
  float inv = 1.0f / fmaxf((float)cnt, 1.0f);
  u32x4 o;
#pragma unroll
  for (int w = 0; w < 4; w++)
    o[w] = (u32)f2bf(acc[2 * w] * inv) | ((u32)f2bf(acc[2 * w + 1] * inv) << 16);
  ((u32x4*)aggb)[(size_t)n * 16 + l16] = o;
}

// ===== MFMA SAGE layer (Cout=128): block = 64 rows x 128 cols, W (K=256) in LDS =====
template<bool WRITE_PRE>
__global__ __launch_bounds__(256)
void sage_mfma_v2_k(const u16* __restrict__ aggb, const u16* __restrict__ xbin,
                    const u16* __restrict__ WbT, const float* __restrict__ bl,
                    u16* __restrict__ xb_out, float* __restrict__ out_pre) {
  __shared__ u16 wsh[128 * 256];        // 64 KB
  int tid = threadIdx.x;
  {
    const u32x4* g = (const u32x4*)WbT;
    u32x4* l = (u32x4*)wsh;
#pragma unroll
    for (int i = 0; i < 16; i++)
      l[tid + i * 256] = g[tid + i * 256];
  }
  __syncthreads();

  int wave = tid >> 6;
  int lane = tid & 63;
  int quad = lane >> 4;
  int m16  = lane & 15;
  int r0 = blockIdx.x * 64 + wave * 16;

  int rowA = min(r0 + m16, NN - 1);
  const u16* pa = aggb + (size_t)rowA * 128 + quad * 8;
  const u16* px = xbin + (size_t)rowA * 128 + quad * 8;
  bf16x8 a[8];
#pragma unroll
  for (int j = 0; j < 4; j++) a[j]     = *(const bf16x8*)(pa + j * 32);
#pragma unroll
  for (int j = 0; j < 4; j++) a[4 + j] = *(const bf16x8*)(px + j * 32);

  f32x4 acc[8];
#pragma unroll
  for (int nt = 0; nt < 8; nt++) acc[nt] = (f32x4){0.f, 0.f, 0.f, 0.f};

  int swz = m16 & 7;
#pragma unroll
  for (int ks = 0; ks < 8; ks++) {
#pragma unroll
    for (int nt = 0; nt < 8; nt++) {
      const u16* bp = wsh + (nt * 16 + m16) * 256 + (((quad + ks * 4) ^ swz) << 3);
      bf16x8 b = *(const bf16x8*)bp;
      acc[nt] = __builtin_amdgcn_mfma_f32_16x16x32_bf16(a[ks], b, acc[nt], 0, 0, 0);
    }
  }

  float bv[8];
#pragma unroll
  for (int nt = 0; nt < 8; nt++) bv[nt] = bl[nt * 16 + m16];

  int rbase = r0 + quad * 4;
#pragma unroll
  for (int r = 0; r < 4; r++) {
    int row = rbase + r;
    if (row < NN) {
#pragma unroll
      for (int nt = 0; nt < 8; nt++) {
        int col = nt * 16 + m16;
        float v = acc[nt][r] + bv[nt];
        if (WRITE_PRE) out_pre[(size_t)row * 128 + col] = v;
        xb_out[(size_t)row * 128 + col] = f2bf(fmaxf(v, 0.f));
      }
    }
  }
}

// ================= merged tail: {gemm64 | pool} -> bar -> gather8 -> bar -> sage64f ====
// 1024 blocks x 256 thr, __launch_bounds__(256,4) => <=128 VGPR => 4 blocks/CU
// guaranteed co-resident (16 KB LDS, 16 waves/CU) -> spin barrier safe.
__global__ __launch_bounds__(256, 4)
void tail_k(const u16* __restrict__ xb2, const int* __restrict__ cluster,
            float* __restrict__ g, const u16* __restrict__ WlT2,
            u16* __restrict__ y2, const int* __restrict__ row_ptr,
            const int* __restrict__ perm, u16* __restrict__ aggy,
            const u16* __restrict__ WrT2, const float* __restrict__ bl2,
            float* __restrict__ out, int* __restrict__ bars) {
  __shared__ u16 wsh[64 * 128];         // 16 KB
  int tid = threadIdx.x;
  int wave = tid >> 6;
  int lane = tid & 63;
  int quad = lane >> 4;
  int m16  = lane & 15;
  int swz = m16 & 7;

  // ---- phase A item 1: gemm64 (wb<782) or pool (wb in [782,1294)) ----
  int wb = blockIdx.x;
  if (wb < 782) {
    const u32x4* gw = (const u32x4*)WlT2;
    u32x4* l = (u32x4*)wsh;
#pragma unroll
    for (int i = 0; i < 4; i++) l[tid + i * 256] = gw[tid + i * 256];
    __syncthreads();
    int r0 = wb * 64 + wave * 16;
    int rowA = min(r0 + m16, NN - 1);
    const u16* px = xb2 + (size_t)rowA * 128 + quad * 8;
    bf16x8 a[4];
#pragma unroll
    for (int j = 0; j < 4; j++) a[j] = *(const bf16x8*)(px + j * 32);
    f32x4 acc[4];
#pragma unroll
    for (int nt = 0; nt < 4; nt++) acc[nt] = (f32x4){0.f, 0.f, 0.f, 0.f};
#pragma unroll
    for (int ks = 0; ks < 4; ks++) {
#pragma unroll
      for (int nt = 0; nt < 4; nt++) {
        const u16* bp = wsh + (nt * 16 + m16) * 128 + (((ks * 4 + quad) ^ swz) << 3);
        bf16x8 b = *(const bf16x8*)bp;
        acc[nt] = __builtin_amdgcn_mfma_f32_16x16x32_bf16(a[ks], b, acc[nt], 0, 0, 0);
      }
    }
    int rbase = r0 + quad * 4;
#pragma unroll
    for (int r = 0; r < 4; r++) {
      int row = rbase + r;
      if (row < NN) {
#pragma unroll
        for (int nt = 0; nt < 4; nt++)
          y2[(size_t)row * 64 + nt * 16 + m16] = f2bf(acc[nt][r]);
      }
    }
  } else if (wb < 1294) {
    // pool for graph wb-782
    float* shf = (float*)wsh;
    int gid = wb - 782;
    int ch = tid & 127;
    int half = tid >> 7;
    int lo = 0, hi = NN;
    while (lo < hi) { int mid = (lo + hi) >> 1; if (cluster[mid] < gid) lo = mid + 1; else hi = mid; }
    int beg = lo;
    hi = NN;
    while (lo < hi) { int mid = (lo + hi) >> 1; if (cluster[mid] < gid + 1) lo = mid + 1; else hi = mid; }
    int end = lo;
    float s0 = 0.f, s1 = 0.f;
    int n = beg + half;
    for (; n + 2 < end; n += 4) {
      s0 += bf2f(xb2[(size_t)n * 128 + ch]);
      s1 += bf2f(xb2[(size_t)(n + 2) * 128 + ch]);
    }
    if (n < end) s0 += bf2f(xb2[(size_t)n * 128 + ch]);
    __syncthreads();
    shf[tid] = s0 + s1;
    __syncthreads();
    if (tid < 128) {
      float s = shf[tid] + shf[tid + 128];
      g[gid * 128 + tid] = s / fmaxf((float)(end - beg), 1.0f);
    }
  }
  // ---- phase A item 2: remaining pools (blocks < 270) ----
  {
    int wb2 = blockIdx.x + 1024;
    if (wb2 < 1294) {
      float* shf = (float*)wsh;
      int gid = wb2 - 782;
      int ch = tid & 127;
      int half = tid >> 7;
      int lo = 0, hi = NN;
      while (lo < hi) { int mid = (lo + hi) >> 1; if (cluster[mid] < gid) lo = mid + 1; else hi = mid; }
      int beg = lo;
      hi = NN;
      while (lo < hi) { int mid = (lo + hi) >> 1; if (cluster[mid] < gid + 1) lo = mid + 1; else hi = mid; }
      int end = lo;
      float s0 = 0.f, s1 = 0.f;
      int n = beg + half;
      for (; n + 2 < end; n += 4) {
        s0 += bf2f(xb2[(size_t)n * 128 + ch]);
        s1 += bf2f(xb2[(size_t)(n + 2) * 128 + ch]);
      }
      if (n < end) s0 += bf2f(xb2[(size_t)n * 128 + ch]);
      __syncthreads();
      shf[tid] = s0 + s1;
      __syncthreads();
      if (tid < 128) {
        float s = shf[tid] + shf[tid + 128];
        g[gid * 128 + tid] = s / fmaxf((float)(end - beg), 1.0f);
      }
    }
  }
  gridbar(&bars[2], 1024);

  // ---- phase B: gather8 over y2 (items 0..1562) ----
  for (int it = 0; it < 2; it++) {
    int vb = blockIdx.x + it * 1024;
    if (vb >= 1563) break;
    int grp8 = lane >> 3;
    int li   = lane & 7;
    int n = (vb * 4 + wave) * 8 + grp8;
    int ns = min(n, NN - 1);
    int beg = row_ptr[ns];
    int cnt = row_ptr[ns + 1] - beg;
    int beg_s = min(beg, NE - 1);
    int last = max(cnt - 1, 0);
    int m = max(cnt, __shfl_xor(cnt, 8));
    m = max(m, __shfl_xor(m, 16));
    int jmax = max(m, __shfl_xor(m, 32));
    float acc[8];
#pragma unroll
    for (int i = 0; i < 8; i++) acc[i] = 0.f;
    const u32x4* xv = (const u32x4*)y2;
    for (int base = 0; base < jmax; base += 8) {
      int idx[8];
#pragma unroll
      for (int j = 0; j < 8; j++) idx[j] = perm[beg_s + min(base + j, last)];
      u32x4 v[8];
#pragma unroll
      for (int j = 0; j < 8; j++) v[j] = xv[(size_t)idx[j] * 8 + li];
#pragma unroll
      for (int j = 0; j < 8; j++) {
        bool live = (base + j) < cnt;
#pragma unroll
        for (int w = 0; w < 4; w++) {
          u32 u = v[j][w];
          acc[2 * w]     += live ? __uint_as_float(u << 16) : 0.f;
          acc[2 * w + 1] += live ? __uint_as_float(u & 0xffff0000u) : 0.f;
        }
      }
    }
    float inv = 1.0f / fmaxf((float)cnt, 1.0f);
    u32x4 o;
#pragma unroll
    for (int w = 0; w < 4; w++)
      o[w] = (u32)f2bf(acc[2 * w] * inv) | ((u32)f2bf(acc[2 * w + 1] * inv) << 16);
    if (n < NN) ((u32x4*)aggy)[(size_t)n * 8 + li] = o;
  }
  gridbar(&bars[3], 1024);

  // ---- phase C: sage64f (blocks < 782) ----
  if (blockIdx.x < 782) {
    const u32x4* gw = (const u32x4*)WrT2;
    u32x4* l = (u32x4*)wsh;
#pragma unroll
    for (int i = 0; i < 4; i++) l[tid + i * 256] = gw[tid + i * 256];
    __syncthreads();

    int r0 = blockIdx.x * 64 + wave * 16;
    int rowA = min(r0 + m16, NN - 1);
    const u16* px = xb2 + (size_t)rowA * 128 + quad * 8;
    bf16x8 a[4];
#pragma unroll
    for (int j = 0; j < 4; j++) a[j] = *(const bf16x8*)(px + j * 32);
    f32x4 acc[4];
#pragma unroll
    for (int nt = 0; nt < 4; nt++) acc[nt] = (f32x4){0.f, 0.f, 0.f, 0.f};
#pragma unroll
    for (int ks = 0; ks < 4; ks++) {
#pragma unroll
      for (int nt = 0; nt < 4; nt++) {
        const u16* bp = wsh + (nt * 16 + m16) * 128 + (((ks * 4 + quad) ^ swz) << 3);
        bf16x8 b = *(const bf16x8*)bp;
        acc[nt] = __builtin_amdgcn_mfma_f32_16x16x32_bf16(a[ks], b, acc[nt], 0, 0, 0);
      }
    }
    float bv[4];
#pragma unroll
    for (int nt = 0; nt < 4; nt++) bv[nt] = bl2[nt * 16 + m16];
    int rbase = r0 + quad * 4;
#pragma unroll
    for (int r = 0; r < 4; r++) {
      int row = rbase + r;
      int rs = min(row, NN - 1);
      float v0 = acc[0][r] + bv[0] + bf2f(aggy[(size_t)rs * 64 + m16]);
      float v1 = acc[1][r] + bv[1] + bf2f(aggy[(size_t)rs * 64 + 16 + m16]);
      float v2 = acc[2][r] + bv[2] + bf2f(aggy[(size_t)rs * 64 + 32 + m16]);
      float v3 = acc[3][r] + bv[3] + bf2f(aggy[(size_t)rs * 64 + 48 + m16]);
      float m = fmaxf(fmaxf(v0, v1), fmaxf(v2, v3));
#pragma unroll
      for (int mk = 1; mk <= 8; mk <<= 1) m = fmaxf(m, __shfl_xor(m, mk));
      float s = __expf(v0 - m) + __expf(v1 - m) + __expf(v2 - m) + __expf(v3 - m);
#pragma unroll
      for (int mk = 1; mk <= 8; mk <<= 1) s += __shfl_xor(s, mk);
      float ls = m + __logf(s);
      if (row < NN) {
        float* orow = out + (size_t)row * 64;
        orow[m16]      = v0 - ls;
        orow[16 + m16] = v1 - ls;
        orow[32 + m16] = v2 - ls;
        orow[48 + m16] = v3 - ls;
      }
    }
  }
}

extern "C" void kernel_launch(void* const* d_in, const int* in_sizes, int n_in,
                              void* d_out, int out_size, void* d_ws, size_t ws_size,
                              hipStream_t stream) {
  const float* x   = (const float*)d_in[0];
  const int*   ei  = (const int*)d_in[1];
  const int*   cl  = (const int*)d_in[2];
  const float* Wl0 = (const float*)d_in[3];
  const float* bl0 = (const float*)d_in[4];
  const float* Wr0 = (const float*)d_in[5];
  const float* Wl1 = (const float*)d_in[6];
  const float* bl1 = (const float*)d_in[7];
  const float* Wr1 = (const float*)d_in[8];
  const float* Wl2 = (const float*)d_in[9];
  const float* bl2 = (const float*)d_in[10];
  const float* Wr2 = (const float*)d_in[11];
  float* out = (float*)d_out;

  char* ws = (char*)d_ws;
  u16*   xb0     = (u16*)  (ws);                  // 12,800,000 B (bf16 of x)
  u16*   xb1     = (u16*)  (ws + 12800000);       // 12,800,000 B (relu layer0)
  u16*   xb2     = (u16*)  (ws + 25600000);       // 12,800,000 B (relu layer1)
  u16*   aggb    = (u16*)  (ws + 38400000);       // 12,800,000 B (layer0/1 agg)
  u16*   y2      = aggb;                          //  6,400,000 B (xb2 @ Wl2, bf16)
  u16*   aggy    = (u16*)  (ws + 44800000);       //  6,400,000 B
  u16*   WbT0    = (u16*)  (ws + 51200000);       //     65,536 B (swizzled, K=256)
  u16*   WbT1    = (u16*)  (ws + 51265536);       //     65,536 B
  u16*   WlT2    = (u16*)  (ws + 51331072);       //     16,384 B (swizzled, K=128)
  u16*   WrT2    = (u16*)  (ws + 51347456);       //     16,384 B
  int*   deg     = (int*)  (ws + 51363840);       //    200,000 B
  int*   bars    = (int*)  (ws + 51563840);       //         16 B (zeroed with deg)
  int*   row_ptr = (int*)  (ws + 51564032);       //    200,004 B (+pad)
  int*   cursor  = (int*)  (ws + 51764736);       //    200,000 B
  int*   perm    = (int*)  (ws + 51964736);       //  2,400,000 B
  int*   bsum    = (int*)  (ws + 54364736);       //        784 B
  // total ~54.4 MB

  float* out_lsm = out;            // [50000,64]
  float* out_pre = out + 3200000;  // [50000,128]
  float* out_g   = out + 9600000;  // [512,128]

  // ---- zero deg + barrier counters (one memset) ----
  hipMemsetAsync(deg, 0, 200016, stream);

  // ---- fused prep (cast x, deg count, all weight casts) ----
  prep_k<<<15164, 256, 0, stream>>>(x, (u32*)xb0, ei, deg,
                                    Wl0, Wr0, WbT0, Wl1, Wr1, WbT1,
                                    Wl2, WlT2, Wr2, WrT2);

  // ---- merged CSR scans + fill (1 dispatch, spin-barriered, 196 blocks) ----
  csr_k<<<196, 256, 0, stream>>>(ei, deg, bsum, row_ptr, cursor, perm, bars);

  // ---- layer 0 ----
  gather4_k<<<3125, 256, 0, stream>>>(xb0, row_ptr, perm, aggb);
  sage_mfma_v2_k<false><<<782, 256, 0, stream>>>(aggb, xb0, WbT0, bl0, xb1, nullptr);

  // ---- layer 1 (pre-relu f32 straight to d_out) ----
  gather4_k<<<3125, 256, 0, stream>>>(xb1, row_ptr, perm, aggb);
  sage_mfma_v2_k<true><<<782, 256, 0, stream>>>(aggb, xb1, WbT1, bl1, xb2, out_pre);

  // ---- merged tail: {gemm64 | pool} -> gather8 -> sage64f (1 dispatch, 1024 blocks) ----
  tail_k<<<1024, 256, 0, stream>>>(xb2, cl, out_g, WlT2, y2, row_ptr, perm,
                                   aggy, WrT2, bl2, out_lsm, bars);
}

// Round 10
// 322.950 us; speedup vs baseline: 1.6465x; 1.6465x over previous
//
#include <hip/hip_runtime.h>
#include <math.h>

#define NN 50000
#define NE 600000
#define NG 512

typedef unsigned int u32;
typedef unsigned short u16;
typedef unsigned char u8;

typedef __attribute__((ext_vector_type(8))) short bf16x8;
typedef __attribute__((ext_vector_type(4))) float f32x4;
typedef __attribute__((ext_vector_type(4))) unsigned int u32x4;

__device__ __forceinline__ float bf2f(u16 u) {
  return __uint_as_float(((u32)u) << 16);
}
__device__ __forceinline__ u16 f2bf(float f) {
  u32 u = __float_as_uint(f);
  u32 lsb = (u >> 16) & 1u;
  u += 0x7fffu + lsb;          // RNE
  return (u16)(u >> 16);
}

// ---- custom fp8 codec (e4m3-style, self-consistent encode/decode) ----
// encode: RNE at bit 20 of f32, exponent window [2^-7, 448], flush-to-zero below.
__device__ __forceinline__ u8 f2q(float f) {
  u32 b = __float_as_uint(f);
  u32 s = (b >> 24) & 0x80u;
  u32 mag = b & 0x7fffffffu;
  u32 lsb = (mag >> 20) & 1u;
  mag += 0x7ffffu + lsb;
  int t = (int)(mag >> 20) - 960;        // (e<<3|m) - 120*8
  u32 em = (t < 0) ? 0u : ((t > 0x7e) ? 0x7eu : (u32)t);
  return (u8)(s | em);
}
// decode byte k of u32: em==0 -> 0, else sign | f32 with exp bias shift
__device__ __forceinline__ float q2f(u32 u, int k) {
  u32 s8 = (u >> (8 * k)) & 0xffu;
  u32 em = s8 & 0x7fu;
  u32 bits = ((s8 & 0x80u) << 24) | ((em << 20) + 0x3c000000u);
  return em ? __uint_as_float(bits) : 0.f;
}

// ================= fused prep: cast x (bf16 + fp8), count degrees, weight casts ========
// blocks [0,12500): cast x ; [12500,14844): deg_count ;
// [14844,14972): castW0 (swz) ; [14972,15100): castW1 (swz) ;
// [15100,15132): WlT2 (swz) ; [15132,15164): WrT2 (swz)
__global__ __launch_bounds__(256)
void prep_k(const float* __restrict__ x, u32* __restrict__ xb, u16* __restrict__ xq16,
            const int* __restrict__ ei, int* __restrict__ deg,
            const float* __restrict__ Wl0, const float* __restrict__ Wr0, u16* __restrict__ WbT0,
            const float* __restrict__ Wl1, const float* __restrict__ Wr1, u16* __restrict__ WbT1,
            const float* __restrict__ Wl2, u16* __restrict__ WlT2,
            const float* __restrict__ Wr2, u16* __restrict__ WrT2) {
  int b = blockIdx.x;
  int tid = threadIdx.x;
  if (b < 12500) {
    int t = b * 256 + tid;                       // 3,200,000 exactly (2 ch per thread)
    float2 v = ((const float2*)x)[t];
    xb[t] = (u32)f2bf(v.x) | ((u32)f2bf(v.y) << 16);
    xq16[t] = (u16)f2q(v.x) | ((u16)f2q(v.y) << 8);
  } else if (b < 14844) {
    int e = (b - 12500) * 256 + tid;
    if (e < NE) atomicAdd(&deg[ei[NE + e]], 1);
  } else if (b < 15100) {
    // K=256 weight cast+transpose, pre-swizzled: WbT[n][k], 16B chunk idx ^= (n&7)
    bool w1 = (b >= 14972);
    int t = (b - (w1 ? 14972 : 14844)) * 256 + tid;   // 128*256
    int n = t >> 8;
    int k = t & 255;
    const float* Wl = w1 ? Wl1 : Wl0;
    const float* Wr = w1 ? Wr1 : Wr0;
    float v = (k < 128) ? Wl[k * 128 + n] : Wr[(k - 128) * 128 + n];
    int c = k >> 3, e = k & 7;
    u16* dst = w1 ? WbT1 : WbT0;
    dst[n * 256 + (((c ^ (n & 7)) << 3) | e)] = f2bf(v);
  } else {
    // K=128 -> 64 cols, pre-swizzled
    bool wr = (b >= 15132);
    int t = (b - (wr ? 15132 : 15100)) * 256 + tid;   // 8192 = 64*128
    int n = t >> 7;
    int k = t & 127;
    const float* W = wr ? Wr2 : Wl2;
    float v = W[k * 64 + n];
    int c = k >> 3, e = k & 7;
    u16* dst = wr ? WrT2 : WlT2;
    dst[n * 128 + (((c ^ (n & 7)) << 3) | e)] = f2bf(v);
  }
}

// ================= CSR scans (round-6 proven) ========
__global__ __launch_bounds__(256)
void scan1_k(const int* __restrict__ deg, int* __restrict__ bsum) {
  __shared__ int s[256];
  int idx = blockIdx.x * 256 + threadIdx.x;
  int v = (idx < NN) ? deg[idx] : 0;
  s[threadIdx.x] = v;
  __syncthreads();
  for (int off = 128; off > 0; off >>= 1) {
    if (threadIdx.x < off) s[threadIdx.x] += s[threadIdx.x + off];
    __syncthreads();
  }
  if (threadIdx.x == 0) bsum[blockIdx.x] = s[0];
}

__global__ __launch_bounds__(256)
void scan2_k(const int* __restrict__ bsum, int* __restrict__ bofs, int* __restrict__ row_ptr) {
  __shared__ int s[256];
  int t = threadIdx.x;
  int v = (t < 196) ? bsum[t] : 0;
  s[t] = v;
  __syncthreads();
  for (int off = 1; off < 256; off <<= 1) {
    int add = (t >= off) ? s[t - off] : 0;
    __syncthreads();
    s[t] += add;
    __syncthreads();
  }
  if (t < 196) bofs[t] = s[t] - v;     // exclusive
  if (t == 0) row_ptr[NN] = NE;
}

__global__ __launch_bounds__(256)
void scan3_k(const int* __restrict__ deg, const int* __restrict__ bofs,
             int* __restrict__ row_ptr, int* __restrict__ cursor) {
  __shared__ int s[256];
  int idx = blockIdx.x * 256 + threadIdx.x;
  int t = threadIdx.x;
  int v = (idx < NN) ? deg[idx] : 0;
  s[t] = v;
  __syncthreads();
  for (int off = 1; off < 256; off <<= 1) {
    int add = (t >= off) ? s[t - off] : 0;
    __syncthreads();
    s[t] += add;
    __syncthreads();
  }
  if (idx < NN) {
    int p = bofs[blockIdx.x] + s[t] - v;
    row_ptr[idx] = p;
    cursor[idx] = p;
  }
}

__global__ __launch_bounds__(256)
void fill_k(const int* __restrict__ ei, int* __restrict__ cursor, int* __restrict__ perm) {
  int e = blockIdx.x * 256 + threadIdx.x;
  if (e >= NE) return;
  int pos = atomicAdd(&cursor[ei[NE + e]], 1);
  perm[pos] = ei[e];
}

// ===== fp8 gather-mean (128 ch, rows = 128 B = ONE line/edge) =====
// 8 nodes/wave (grp = lane>>3), lane8 owns 16 B (16 channels) of the row; batch-8.
__global__ __launch_bounds__(256)
void gatherq_k(const u8* __restrict__ xq, const int* __restrict__ row_ptr,
               const int* __restrict__ perm, u16* __restrict__ aggb) {
  int wave = threadIdx.x >> 6;
  int lane = threadIdx.x & 63;
  int grp  = lane >> 3;               // 0..7 node slot
  int li   = lane & 7;                // 16B chunk in 128B row
  int n = (blockIdx.x * 4 + wave) * 8 + grp;     // 1563*4*8 = 50016 (tail clamped)
  int ns = min(n, NN - 1);
  int beg = row_ptr[ns];
  int cnt = row_ptr[ns + 1] - beg;
  int beg_s = min(beg, NE - 1);
  int last = max(cnt - 1, 0);
  int m = max(cnt, __shfl_xor(cnt, 8));
  m = max(m, __shfl_xor(m, 16));
  int jmax = max(m, __shfl_xor(m, 32));          // wave-uniform loop bound
  float acc[16];
#pragma unroll
  for (int i = 0; i < 16; i++) acc[i] = 0.f;
  const u32x4* xv = (const u32x4*)xq;            // row = 8 chunks of 16 B
  for (int base = 0; base < jmax; base += 8) {
    int idx[8];
#pragma unroll
    for (int j = 0; j < 8; j++) idx[j] = perm[beg_s + min(base + j, last)];
    u32x4 v[8];
#pragma unroll
    for (int j = 0; j < 8; j++) v[j] = xv[(size_t)idx[j] * 8 + li];
#pragma unroll
    for (int j = 0; j < 8; j++) {
      bool live = (base + j) < cnt;
#pragma unroll
      for (int w = 0; w < 4; w++) {
        u32 u = v[j][w];
#pragma unroll
        for (int k = 0; k < 4; k++) {
          float f = q2f(u, k);
          acc[w * 4 + k] += live ? f : 0.f;
        }
      }
    }
  }
  float inv = 1.0f / fmaxf((float)cnt, 1.0f);
  u32 o[8];
#pragma unroll
  for (int p = 0; p < 8; p++)
    o[p] = (u32)f2bf(acc[2 * p] * inv) | ((u32)f2bf(acc[2 * p + 1] * inv) << 16);
  if (n < NN) {
    u32x4* dst = (u32x4*)(aggb + (size_t)n * 128);
    dst[li * 2]     = (u32x4){o[0], o[1], o[2], o[3]};
    dst[li * 2 + 1] = (u32x4){o[4], o[5], o[6], o[7]};
  }
}

// ===== fp8 gather-mean (64 ch, rows = 64 B = HALF line/edge) for final layer =====
// 16 nodes/wave (grp = lane>>2), lane4 owns 16 B; batch-8. Output aggy bf16.
__global__ __launch_bounds__(256)
void gatherq64_k(const u8* __restrict__ yq, const int* __restrict__ row_ptr,
                 const int* __restrict__ perm, u16* __restrict__ aggy) {
  int wave = threadIdx.x >> 6;
  int lane = threadIdx.x & 63;
  int grp  = lane >> 2;               // 0..15 node slot
  int li   = lane & 3;                // 16B chunk in 64B row
  int n = (blockIdx.x * 4 + wave) * 16 + grp;    // 782*4*16 = 50048 (tail clamped)
  int ns = min(n, NN - 1);
  int beg = row_ptr[ns];
  int cnt = row_ptr[ns + 1] - beg;
  int beg_s = min(beg, NE - 1);
  int last = max(cnt - 1, 0);
  int m = max(cnt, __shfl_xor(cnt, 4));
  m = max(m, __shfl_xor(m, 8));
  m = max(m, __shfl_xor(m, 16));
  int jmax = max(m, __shfl_xor(m, 32));
  float acc[16];
#pragma unroll
  for (int i = 0; i < 16; i++) acc[i] = 0.f;
  const u32x4* xv = (const u32x4*)yq;            // row = 4 chunks of 16 B
  for (int base = 0; base < jmax; base += 8) {
    int idx[8];
#pragma unroll
    for (int j = 0; j < 8; j++) idx[j] = perm[beg_s + min(base + j, last)];
    u32x4 v[8];
#pragma unroll
    for (int j = 0; j < 8; j++) v[j] = xv[(size_t)idx[j] * 4 + li];
#pragma unroll
    for (int j = 0; j < 8; j++) {
      bool live = (base + j) < cnt;
#pragma unroll
      for (int w = 0; w < 4; w++) {
        u32 u = v[j][w];
#pragma unroll
        for (int k = 0; k < 4; k++) {
          float f = q2f(u, k);
          acc[w * 4 + k] += live ? f : 0.f;
        }
      }
    }
  }
  float inv = 1.0f / fmaxf((float)cnt, 1.0f);
  u32 o[8];
#pragma unroll
  for (int p = 0; p < 8; p++)
    o[p] = (u32)f2bf(acc[2 * p] * inv) | ((u32)f2bf(acc[2 * p + 1] * inv) << 16);
  if (n < NN) {
    u32x4* dst = (u32x4*)(aggy + (size_t)n * 64);
    dst[li * 2]     = (u32x4){o[0], o[1], o[2], o[3]};
    dst[li * 2 + 1] = (u32x4){o[4], o[5], o[6], o[7]};
  }
}

// ===== MFMA SAGE layer (Cout=128): block = 64 rows x 128 cols, W (K=256) in LDS =====
// WRITE_XQ: also emit fp8 of relu output (next layer's gather table).
template<bool WRITE_PRE, bool WRITE_XQ>
__global__ __launch_bounds__(256)
void sage_mfma_v2_k(const u16* __restrict__ aggb, const u16* __restrict__ xbin,
                    const u16* __restrict__ WbT, const float* __restrict__ bl,
                    u16* __restrict__ xb_out, float* __restrict__ out_pre,
                    u8* __restrict__ xq_out) {
  __shared__ u16 wsh[128 * 256];        // 64 KB
  int tid = threadIdx.x;
  {
    const u32x4* g = (const u32x4*)WbT;
    u32x4* l = (u32x4*)wsh;
#pragma unroll
    for (int i = 0; i < 16; i++)
      l[tid + i * 256] = g[tid + i * 256];
  }
  __syncthreads();

  int wave = tid >> 6;
  int lane = tid & 63;
  int quad = lane >> 4;
  int m16  = lane & 15;
  int r0 = blockIdx.x * 64 + wave * 16;

  int rowA = min(r0 + m16, NN - 1);
  const u16* pa = aggb + (size_t)rowA * 128 + quad * 8;
  const u16* px = xbin + (size_t)rowA * 128 + quad * 8;
  bf16x8 a[8];
#pragma unroll
  for (int j = 0; j < 4; j++) a[j]     = *(const bf16x8*)(pa + j * 32);
#pragma unroll
  for (int j = 0; j < 4; j++) a[4 + j] = *(const bf16x8*)(px + j * 32);

  f32x4 acc[8];
#pragma unroll
  for (int nt = 0; nt < 8; nt++) acc[nt] = (f32x4){0.f, 0.f, 0.f, 0.f};

  int swz = m16 & 7;
#pragma unroll
  for (int ks = 0; ks < 8; ks++) {
#pragma unroll
    for (int nt = 0; nt < 8; nt++) {
      const u16* bp = wsh + (nt * 16 + m16) * 256 + (((quad + ks * 4) ^ swz) << 3);
      bf16x8 b = *(const bf16x8*)bp;
      acc[nt] = __builtin_amdgcn_mfma_f32_16x16x32_bf16(a[ks], b, acc[nt], 0, 0, 0);
    }
  }

  float bv[8];
#pragma unroll
  for (int nt = 0; nt < 8; nt++) bv[nt] = bl[nt * 16 + m16];

  int rbase = r0 + quad * 4;
#pragma unroll
  for (int r = 0; r < 4; r++) {
    int row = rbase + r;
    if (row < NN) {
#pragma unroll
      for (int nt = 0; nt < 8; nt++) {
        int col = nt * 16 + m16;
        float v = acc[nt][r] + bv[nt];
        if (WRITE_PRE) out_pre[(size_t)row * 128 + col] = v;
        float rl = fmaxf(v, 0.f);
        xb_out[(size_t)row * 128 + col] = f2bf(rl);
        if (WRITE_XQ) xq_out[(size_t)row * 128 + col] = f2q(rl);
      }
    }
  }
}

// ===== merged pool + gemm64 (both read xb2; gemm writes fp8 y2q only) =====
// blocks [0,NG): graph pooling ; [NG, NG+782): y2q = fp8(xb2 @ Wl2)
__global__ __launch_bounds__(256)
void post_k(const u16* __restrict__ xb2, const int* __restrict__ cluster,
            float* __restrict__ g, const u16* __restrict__ WlT2,
            u8* __restrict__ yq) {
  __shared__ u16 wsh[64 * 128];         // 16 KB (gemm blocks); pool reuses as float
  int tid = threadIdx.x;
  if (blockIdx.x < NG) {
    float* sh = (float*)wsh;
    int gid = blockIdx.x;
    int ch = tid & 127;
    int half = tid >> 7;
    int lo = 0, hi = NN;
    while (lo < hi) { int mid = (lo + hi) >> 1; if (cluster[mid] < gid) lo = mid + 1; else hi = mid; }
    int beg = lo;
    hi = NN;
    while (lo < hi) { int mid = (lo + hi) >> 1; if (cluster[mid] < gid + 1) lo = mid + 1; else hi = mid; }
    int end = lo;
    float s0 = 0.f, s1 = 0.f;
    int n = beg + half;
    for (; n + 2 < end; n += 4) {
      s0 += bf2f(xb2[(size_t)n * 128 + ch]);
      s1 += bf2f(xb2[(size_t)(n + 2) * 128 + ch]);
    }
    if (n < end) s0 += bf2f(xb2[(size_t)n * 128 + ch]);
    sh[tid] = s0 + s1;
    __syncthreads();
    if (tid < 128) {
      float s = sh[tid] + sh[tid + 128];
      g[gid * 128 + tid] = s / fmaxf((float)(end - beg), 1.0f);
    }
    return;
  }
  // ---- gemm64: y2q = fp8(xb2 @ Wl2) (K=128 -> 64 cols) ----
  int bid = blockIdx.x - NG;
  {
    const u32x4* gw = (const u32x4*)WlT2;
    u32x4* l = (u32x4*)wsh;
#pragma unroll
    for (int i = 0; i < 4; i++)
      l[tid + i * 256] = gw[tid + i * 256];
  }
  __syncthreads();

  int wave = tid >> 6;
  int lane = tid & 63;
  int quad = lane >> 4;
  int m16  = lane & 15;
  int r0 = bid * 64 + wave * 16;

  int rowA = min(r0 + m16, NN - 1);
  const u16* px = xb2 + (size_t)rowA * 128 + quad * 8;
  bf16x8 a[4];
#pragma unroll
  for (int j = 0; j < 4; j++) a[j] = *(const bf16x8*)(px + j * 32);

  f32x4 acc[4];
#pragma unroll
  for (int nt = 0; nt < 4; nt++) acc[nt] = (f32x4){0.f, 0.f, 0.f, 0.f};

  int swz = m16 & 7;
#pragma unroll
  for (int ks = 0; ks < 4; ks++) {
#pragma unroll
    for (int nt = 0; nt < 4; nt++) {
      const u16* bp = wsh + (nt * 16 + m16) * 128 + (((ks * 4 + quad) ^ swz) << 3);
      bf16x8 b = *(const bf16x8*)bp;
      acc[nt] = __builtin_amdgcn_mfma_f32_16x16x32_bf16(a[ks], b, acc[nt], 0, 0, 0);
    }
  }

  int rbase = r0 + quad * 4;
#pragma unroll
  for (int r = 0; r < 4; r++) {
    int row = rbase + r;
    if (row < NN) {
#pragma unroll
      for (int nt = 0; nt < 4; nt++)
        yq[(size_t)row * 64 + nt * 16 + m16] = f2q(acc[nt][r]);
    }
  }
}

// ===== final layer: out = log_softmax(aggY + bl2 + xb2 @ Wr2) =====
__global__ __launch_bounds__(256)
void sage64f_k(const u16* __restrict__ aggy, const u16* __restrict__ xbin,
               const u16* __restrict__ WT, const float* __restrict__ bl,
               float* __restrict__ out) {
  __shared__ u16 wsh[64 * 128];         // 16 KB
  int tid = threadIdx.x;
  {
    const u32x4* g = (const u32x4*)WT;
    u32x4* l = (u32x4*)wsh;
#pragma unroll
    for (int i = 0; i < 4; i++)
      l[tid + i * 256] = g[tid + i * 256];
  }
  __syncthreads();

  int wave = tid >> 6;
  int lane = tid & 63;
  int quad = lane >> 4;
  int m16  = lane & 15;
  int r0 = blockIdx.x * 64 + wave * 16;

  int rowA = min(r0 + m16, NN - 1);
  const u16* px = xbin + (size_t)rowA * 128 + quad * 8;
  bf16x8 a[4];
#pragma unroll
  for (int j = 0; j < 4; j++) a[j] = *(const bf16x8*)(px + j * 32);

  f32x4 acc[4];
#pragma unroll
  for (int nt = 0; nt < 4; nt++) acc[nt] = (f32x4){0.f, 0.f, 0.f, 0.f};

  int swz = m16 & 7;
#pragma unroll
  for (int ks = 0; ks < 4; ks++) {
#pragma unroll
    for (int nt = 0; nt < 4; nt++) {
      const u16* bp = wsh + (nt * 16 + m16) * 128 + (((ks * 4 + quad) ^ swz) << 3);
      bf16x8 b = *(const bf16x8*)bp;
      acc[nt] = __builtin_amdgcn_mfma_f32_16x16x32_bf16(a[ks], b, acc[nt], 0, 0, 0);
    }
  }

  float bv[4];
#pragma unroll
  for (int nt = 0; nt < 4; nt++) bv[nt] = bl[nt * 16 + m16];

  int rbase = r0 + quad * 4;
#pragma unroll
  for (int r = 0; r < 4; r++) {
    int row = rbase + r;
    int rs = min(row, NN - 1);
    float v0 = acc[0][r] + bv[0] + bf2f(aggy[(size_t)rs * 64 + m16]);
    float v1 = acc[1][r] + bv[1] + bf2f(aggy[(size_t)rs * 64 + 16 + m16]);
    float v2 = acc[2][r] + bv[2] + bf2f(aggy[(size_t)rs * 64 + 32 + m16]);
    float v3 = acc[3][r] + bv[3] + bf2f(aggy[(size_t)rs * 64 + 48 + m16]);
    float m = fmaxf(fmaxf(v0, v1), fmaxf(v2, v3));
#pragma unroll
    for (int mk = 1; mk <= 8; mk <<= 1) m = fmaxf(m, __shfl_xor(m, mk));
    float s = __expf(v0 - m) + __expf(v1 - m) + __expf(v2 - m) + __expf(v3 - m);
#pragma unroll
    for (int mk = 1; mk <= 8; mk <<= 1) s += __shfl_xor(s, mk);
    float ls = m + __logf(s);
    if (row < NN) {
      float* orow = out + (size_t)row * 64;
      orow[m16]      = v0 - ls;
      orow[16 + m16] = v1 - ls;
      orow[32 + m16] = v2 - ls;
      orow[48 + m16] = v3 - ls;
    }
  }
}

extern "C" void kernel_launch(void* const* d_in, const int* in_sizes, int n_in,
                              void* d_out, int out_size, void* d_ws, size_t ws_size,
                              hipStream_t stream) {
  const float* x   = (const float*)d_in[0];
  const int*   ei  = (const int*)d_in[1];
  const int*   cl  = (const int*)d_in[2];
  const float* Wl0 = (const float*)d_in[3];
  const float* bl0 = (const float*)d_in[4];
  const float* Wr0 = (const float*)d_in[5];
  const float* Wl1 = (const float*)d_in[6];
  const float* bl1 = (const float*)d_in[7];
  const float* Wr1 = (const float*)d_in[8];
  const float* Wl2 = (const float*)d_in[9];
  const float* bl2 = (const float*)d_in[10];
  const float* Wr2 = (const float*)d_in[11];
  float* out = (float*)d_out;

  char* ws = (char*)d_ws;
  u16*   xb0     = (u16*)  (ws);                  // 12,800,000 B (bf16 of x)
  u16*   xb1     = (u16*)  (ws + 12800000);       // 12,800,000 B (relu layer0)
  u16*   xb2     = (u16*)  (ws + 25600000);       // 12,800,000 B (relu layer1)
  // xq (fp8 gather table, 6.4 MB) lives in xb2's first half: written by prep (xq0)
  // and sage-L0 (xq1), last READ by the L1 gather, then overwritten when sage-L1
  // writes xb2. No overlap within any single kernel.
  u8*    xq      = (u8*)   (ws + 25600000);
  u16*   aggb    = (u16*)  (ws + 38400000);       // 12,800,000 B (L0/L1 agg)
  u8*    y2q     = (u8*)   (ws + 38400000);       //  3,200,000 B (fp8 xb2@Wl2; aggb dead)
  u16*   aggy    = (u16*)  (ws + 44800000);       //  6,400,000 B (aggb second half, dead)
  u16*   WbT0    = (u16*)  (ws + 51200000);       //     65,536 B (swizzled, K=256)
  u16*   WbT1    = (u16*)  (ws + 51265536);       //     65,536 B
  u16*   WlT2    = (u16*)  (ws + 51331072);       //     16,384 B (swizzled, K=128)
  u16*   WrT2    = (u16*)  (ws + 51347456);       //     16,384 B
  int*   deg     = (int*)  (ws + 51363840);       //    200,000 B
  int*   row_ptr = (int*)  (ws + 51564032);       //    200,004 B (+pad)
  int*   cursor  = (int*)  (ws + 51764736);       //    200,000 B
  int*   perm    = (int*)  (ws + 51964736);       //  2,400,000 B
  int*   bsum    = (int*)  (ws + 54364736);       //        784 B
  int*   bofs    = (int*)  (ws + 54365568);       //        784 B
  // total ~54.4 MB (unchanged)

  float* out_lsm = out;            // [50000,64]
  float* out_pre = out + 3200000;  // [50000,128]
  float* out_g   = out + 9600000;  // [512,128]

  // ---- fused prep (cast x bf16+fp8, deg count, all weight casts) ----
  hipMemsetAsync(deg, 0, 200000, stream);
  prep_k<<<15164, 256, 0, stream>>>(x, (u32*)xb0, (u16*)xq, ei, deg,
                                    Wl0, Wr0, WbT0, Wl1, Wr1, WbT1,
                                    Wl2, WlT2, Wr2, WrT2);

  // ---- CSR scans + fill (round-6 proven) ----
  scan1_k<<<196, 256, 0, stream>>>(deg, bsum);
  scan2_k<<<1, 256, 0, stream>>>(bsum, bofs, row_ptr);
  scan3_k<<<196, 256, 0, stream>>>(deg, bofs, row_ptr, cursor);
  fill_k<<<2344, 256, 0, stream>>>(ei, cursor, perm);

  // ---- layer 0: fp8 gather (1 line/edge) + MFMA; epilogue writes xq1 ----
  gatherq_k<<<1563, 256, 0, stream>>>(xq, row_ptr, perm, aggb);
  sage_mfma_v2_k<false, true><<<782, 256, 0, stream>>>(aggb, xb0, WbT0, bl0, xb1, nullptr, xq);

  // ---- layer 1: fp8 gather + MFMA (pre-relu f32 straight to d_out) ----
  gatherq_k<<<1563, 256, 0, stream>>>(xq, row_ptr, perm, aggb);
  sage_mfma_v2_k<true, false><<<782, 256, 0, stream>>>(aggb, xb1, WbT1, bl1, xb2, out_pre, nullptr);

  // ---- pooling + y2q GEMM (merged, both read xb2) ----
  post_k<<<NG + 782, 256, 0, stream>>>(xb2, cl, out_g, WlT2, y2q);

  // ---- final layer via linearity: aggY = gather-mean(fp8 y2, 64B rows);
  //      out = log_softmax(aggY + bl2 + xb2@Wr2) ----
  gatherq64_k<<<782, 256, 0, stream>>>(y2q, row_ptr, perm, aggy);
  sage64f_k<<<782, 256, 0, stream>>>(aggy, xb2, WrT2, bl2, out_lsm);
}

// Round 11
// 312.507 us; speedup vs baseline: 1.7015x; 1.0334x over previous
//
#include <hip/hip_runtime.h>
#include <math.h>

#define NN 50000
#define NE 600000
#define NG 512

typedef unsigned int u32;
typedef unsigned short u16;
typedef unsigned char u8;

typedef __attribute__((ext_vector_type(8))) short bf16x8;
typedef __attribute__((ext_vector_type(4))) float f32x4;
typedef __attribute__((ext_vector_type(4))) unsigned int u32x4;

__device__ __forceinline__ float bf2f(u16 u) {
  return __uint_as_float(((u32)u) << 16);
}
__device__ __forceinline__ u16 f2bf(float f) {
  u32 u = __float_as_uint(f);
  u32 lsb = (u >> 16) & 1u;
  u += 0x7fffu + lsb;          // RNE
  return (u16)(u >> 16);
}

// ---- custom fp8 codec (e4m3-style, self-consistent; validated round 10) ----
__device__ __forceinline__ u8 f2q(float f) {
  u32 b = __float_as_uint(f);
  u32 s = (b >> 24) & 0x80u;
  u32 mag = b & 0x7fffffffu;
  u32 lsb = (mag >> 20) & 1u;
  mag += 0x7ffffu + lsb;
  int t = (int)(mag >> 20) - 960;        // (e<<3|m) - 120*8
  u32 em = (t < 0) ? 0u : ((t > 0x7e) ? 0x7eu : (u32)t);
  return (u8)(s | em);
}
__device__ __forceinline__ float q2f(u32 u, int k) {
  u32 s8 = (u >> (8 * k)) & 0xffu;
  u32 em = s8 & 0x7fu;
  u32 bits = ((s8 & 0x80u) << 24) | ((em << 20) + 0x3c000000u);
  return em ? __uint_as_float(bits) : 0.f;
}

// ================= fused prep: cast x (bf16+fp8), count degrees, weight casts ========
__global__ __launch_bounds__(256)
void prep_k(const float* __restrict__ x, u32* __restrict__ xb, u16* __restrict__ xq16,
            const int* __restrict__ ei, int* __restrict__ deg,
            const float* __restrict__ Wl0, const float* __restrict__ Wr0, u16* __restrict__ WbT0,
            const float* __restrict__ Wl1, const float* __restrict__ Wr1, u16* __restrict__ WbT1,
            const float* __restrict__ Wl2, u16* __restrict__ WlT2,
            const float* __restrict__ Wr2, u16* __restrict__ WrT2) {
  int b = blockIdx.x;
  int tid = threadIdx.x;
  if (b < 12500) {
    int t = b * 256 + tid;                       // 3,200,000 exactly (2 ch per thread)
    float2 v = ((const float2*)x)[t];
    xb[t] = (u32)f2bf(v.x) | ((u32)f2bf(v.y) << 16);
    xq16[t] = (u16)f2q(v.x) | ((u16)f2q(v.y) << 8);
  } else if (b < 14844) {
    int e = (b - 12500) * 256 + tid;
    if (e < NE) atomicAdd(&deg[ei[NE + e]], 1);
  } else if (b < 15100) {
    bool w1 = (b >= 14972);
    int t = (b - (w1 ? 14972 : 14844)) * 256 + tid;   // 128*256
    int n = t >> 8;
    int k = t & 255;
    const float* Wl = w1 ? Wl1 : Wl0;
    const float* Wr = w1 ? Wr1 : Wr0;
    float v = (k < 128) ? Wl[k * 128 + n] : Wr[(k - 128) * 128 + n];
    int c = k >> 3, e = k & 7;
    u16* dst = w1 ? WbT1 : WbT0;
    dst[n * 256 + (((c ^ (n & 7)) << 3) | e)] = f2bf(v);
  } else {
    bool wr = (b >= 15132);
    int t = (b - (wr ? 15132 : 15100)) * 256 + tid;   // 8192 = 64*128
    int n = t >> 7;
    int k = t & 127;
    const float* W = wr ? Wr2 : Wl2;
    float v = W[k * 64 + n];
    int c = k >> 3, e = k & 7;
    u16* dst = wr ? WrT2 : WlT2;
    dst[n * 128 + (((c ^ (n & 7)) << 3) | e)] = f2bf(v);
  }
}

// ================= CSR scans (round-6 proven) ========
__global__ __launch_bounds__(256)
void scan1_k(const int* __restrict__ deg, int* __restrict__ bsum) {
  __shared__ int s[256];
  int idx = blockIdx.x * 256 + threadIdx.x;
  int v = (idx < NN) ? deg[idx] : 0;
  s[threadIdx.x] = v;
  __syncthreads();
  for (int off = 128; off > 0; off >>= 1) {
    if (threadIdx.x < off) s[threadIdx.x] += s[threadIdx.x + off];
    __syncthreads();
  }
  if (threadIdx.x == 0) bsum[blockIdx.x] = s[0];
}

__global__ __launch_bounds__(256)
void scan2_k(const int* __restrict__ bsum, int* __restrict__ bofs, int* __restrict__ row_ptr) {
  __shared__ int s[256];
  int t = threadIdx.x;
  int v = (t < 196) ? bsum[t] : 0;
  s[t] = v;
  __syncthreads();
  for (int off = 1; off < 256; off <<= 1) {
    int add = (t >= off) ? s[t - off] : 0;
    __syncthreads();
    s[t] += add;
    __syncthreads();
  }
  if (t < 196) bofs[t] = s[t] - v;     // exclusive
  if (t == 0) row_ptr[NN] = NE;
}

__global__ __launch_bounds__(256)
void scan3_k(const int* __restrict__ deg, const int* __restrict__ bofs,
             int* __restrict__ row_ptr, int* __restrict__ cursor) {
  __shared__ int s[256];
  int idx = blockIdx.x * 256 + threadIdx.x;
  int t = threadIdx.x;
  int v = (idx < NN) ? deg[idx] : 0;
  s[t] = v;
  __syncthreads();
  for (int off = 1; off < 256; off <<= 1) {
    int add = (t >= off) ? s[t - off] : 0;
    __syncthreads();
    s[t] += add;
    __syncthreads();
  }
  if (idx < NN) {
    int p = bofs[blockIdx.x] + s[t] - v;
    row_ptr[idx] = p;
    cursor[idx] = p;
  }
}

__global__ __launch_bounds__(256)
void fill_k(const int* __restrict__ ei, int* __restrict__ cursor, int* __restrict__ perm) {
  int e = blockIdx.x * 256 + threadIdx.x;
  if (e >= NE) return;
  int pos = atomicAdd(&cursor[ei[NE + e]], 1);
  perm[pos] = ei[e];
}

// ===== fp8 gather-mean, FULL-CONCURRENCY shape: 12500 waves, 4 nodes/wave =====
// lane = (grp:2 | jj:1 | li:3). Each dwordx4 loads 2 neighbors (parity jj) x 4 nodes
// = 8 distinct 128 B rows = 1 line/edge. Batch of 16 neighbors: 8 instrs, 8 KB in
// flight per wave (identical MLP to proven gather4). Final shfl_xor(8) combines
// even/odd-neighbor partials; jj==0 lanes write the bf16 agg row.
__global__ __launch_bounds__(256)
void gatherq12_k(const u8* __restrict__ xq, const int* __restrict__ row_ptr,
                 const int* __restrict__ perm, u16* __restrict__ aggb) {
  int wave = threadIdx.x >> 6;
  int lane = threadIdx.x & 63;
  int grp  = lane >> 4;               // node slot 0..3
  int jj   = (lane >> 3) & 1;         // neighbor parity
  int li   = lane & 7;                // 16B chunk in 128B row
  int n = (blockIdx.x * 4 + wave) * 4 + grp;     // 3125*4*4 = 50000 exact
  int beg = row_ptr[n];
  int cnt = row_ptr[n + 1] - beg;
  int beg_s = min(beg, NE - 1);                  // safe base for clamped reads
  int last = max(cnt - 1, 0);
  int m = max(cnt, __shfl_xor(cnt, 16));
  int jmax = max(m, __shfl_xor(m, 32));          // wave-uniform loop bound
  float acc[16];
#pragma unroll
  for (int i = 0; i < 16; i++) acc[i] = 0.f;
  const u32x4* xv = (const u32x4*)xq;            // row = 8 chunks of 16 B
  for (int base = 0; base < jmax; base += 16) {
    int e8[8];
#pragma unroll
    for (int j = 0; j < 8; j++) e8[j] = base + j * 2 + jj;
    int idx[8];
#pragma unroll
    for (int j = 0; j < 8; j++) idx[j] = perm[beg_s + min(e8[j], last)];
    u32x4 v[8];
#pragma unroll
    for (int j = 0; j < 8; j++) v[j] = xv[(size_t)idx[j] * 8 + li];
#pragma unroll
    for (int j = 0; j < 8; j++) {
      bool live = e8[j] < cnt;
#pragma unroll
      for (int w = 0; w < 4; w++) {
        u32 u = v[j][w];
#pragma unroll
        for (int k = 0; k < 4; k++) {
          float f = q2f(u, k);
          acc[w * 4 + k] += live ? f : 0.f;
        }
      }
    }
  }
  // combine even/odd-neighbor partials (partner lane = lane ^ 8)
#pragma unroll
  for (int i = 0; i < 16; i++) acc[i] += __shfl_xor(acc[i], 8);
  float inv = 1.0f / fmaxf((float)cnt, 1.0f);
  if (jj == 0) {
    u32 o[8];
#pragma unroll
    for (int p = 0; p < 8; p++)
      o[p] = (u32)f2bf(acc[2 * p] * inv) | ((u32)f2bf(acc[2 * p + 1] * inv) << 16);
    u32x4* dst = (u32x4*)(aggb + (size_t)n * 128);
    dst[li * 2]     = (u32x4){o[0], o[1], o[2], o[3]};
    dst[li * 2 + 1] = (u32x4){o[4], o[5], o[6], o[7]};
  }
}

// ===== bf16 gather-mean (64 ch rows = 128 B = ONE line/edge), round-6 proven =====
__global__ __launch_bounds__(256)
void gather8_k(const u16* __restrict__ yb, const int* __restrict__ row_ptr,
               const int* __restrict__ perm, u16* __restrict__ aggy) {
  int wave = threadIdx.x >> 6;
  int lane = threadIdx.x & 63;
  int grp  = lane >> 3;               // 0..7
  int li   = lane & 7;
  int n = (blockIdx.x * 4 + wave) * 8 + grp;     // 1563*4*8 = 50016 (tail clamped)
  int ns = min(n, NN - 1);
  int beg = row_ptr[ns];
  int cnt = row_ptr[ns + 1] - beg;
  int beg_s = min(beg, NE - 1);
  int last = max(cnt - 1, 0);
  int m = max(cnt, __shfl_xor(cnt, 8));
  m = max(m, __shfl_xor(m, 16));
  int jmax = max(m, __shfl_xor(m, 32));          // wave-uniform loop bound
  float acc[8];
#pragma unroll
  for (int i = 0; i < 8; i++) acc[i] = 0.f;
  const u32x4* xv = (const u32x4*)yb;            // row = 8 chunks of 16 B
  for (int base = 0; base < jmax; base += 8) {
    int idx[8];
#pragma unroll
    for (int j = 0; j < 8; j++) idx[j] = perm[beg_s + min(base + j, last)];
    u32x4 v[8];
#pragma unroll
    for (int j = 0; j < 8; j++) v[j] = xv[(size_t)idx[j] * 8 + li];
#pragma unroll
    for (int j = 0; j < 8; j++) {
      bool live = (base + j) < cnt;
#pragma unroll
      for (int w = 0; w < 4; w++) {
        u32 u = v[j][w];
        acc[2 * w]     += live ? __uint_as_float(u << 16) : 0.f;
        acc[2 * w + 1] += live ? __uint_as_float(u & 0xffff0000u) : 0.f;
      }
    }
  }
  float inv = 1.0f / fmaxf((float)cnt, 1.0f);
  u32x4 o;
#pragma unroll
  for (int w = 0; w < 4; w++)
    o[w] = (u32)f2bf(acc[2 * w] * inv) | ((u32)f2bf(acc[2 * w + 1] * inv) << 16);
  if (n < NN) ((u32x4*)aggy)[(size_t)n * 8 + li] = o;
}

// ===== MFMA SAGE layer (Cout=128): block = 64 rows x 128 cols, W (K=256) in LDS =====
// WRITE_XQ: also emit fp8 of relu output (next layer's gather table).
template<bool WRITE_PRE, bool WRITE_XQ>
__global__ __launch_bounds__(256)
void sage_mfma_v2_k(const u16* __restrict__ aggb, const u16* __restrict__ xbin,
                    const u16* __restrict__ WbT, const float* __restrict__ bl,
                    u16* __restrict__ xb_out, float* __restrict__ out_pre,
                    u8* __restrict__ xq_out) {
  __shared__ u16 wsh[128 * 256];        // 64 KB
  int tid = threadIdx.x;
  {
    const u32x4* g = (const u32x4*)WbT;
    u32x4* l = (u32x4*)wsh;
#pragma unroll
    for (int i = 0; i < 16; i++)
      l[tid + i * 256] = g[tid + i * 256];
  }
  __syncthreads();

  int wave = tid >> 6;
  int lane = tid & 63;
  int quad = lane >> 4;
  int m16  = lane & 15;
  int r0 = blockIdx.x * 64 + wave * 16;

  int rowA = min(r0 + m16, NN - 1);
  const u16* pa = aggb + (size_t)rowA * 128 + quad * 8;
  const u16* px = xbin + (size_t)rowA * 128 + quad * 8;
  bf16x8 a[8];
#pragma unroll
  for (int j = 0; j < 4; j++) a[j]     = *(const bf16x8*)(pa + j * 32);
#pragma unroll
  for (int j = 0; j < 4; j++) a[4 + j] = *(const bf16x8*)(px + j * 32);

  f32x4 acc[8];
#pragma unroll
  for (int nt = 0; nt < 8; nt++) acc[nt] = (f32x4){0.f, 0.f, 0.f, 0.f};

  int swz = m16 & 7;
#pragma unroll
  for (int ks = 0; ks < 8; ks++) {
#pragma unroll
    for (int nt = 0; nt < 8; nt++) {
      const u16* bp = wsh + (nt * 16 + m16) * 256 + (((quad + ks * 4) ^ swz) << 3);
      bf16x8 b = *(const bf16x8*)bp;
      acc[nt] = __builtin_amdgcn_mfma_f32_16x16x32_bf16(a[ks], b, acc[nt], 0, 0, 0);
    }
  }

  float bv[8];
#pragma unroll
  for (int nt = 0; nt < 8; nt++) bv[nt] = bl[nt * 16 + m16];

  int rbase = r0 + quad * 4;
#pragma unroll
  for (int r = 0; r < 4; r++) {
    int row = rbase + r;
    if (row < NN) {
#pragma unroll
      for (int nt = 0; nt < 8; nt++) {
        int col = nt * 16 + m16;
        float v = acc[nt][r] + bv[nt];
        if (WRITE_PRE) out_pre[(size_t)row * 128 + col] = v;
        float rl = fmaxf(v, 0.f);
        xb_out[(size_t)row * 128 + col] = f2bf(rl);
        if (WRITE_XQ) xq_out[(size_t)row * 128 + col] = f2q(rl);
      }
    }
  }
}

// ===== merged pool + gemm64 (round-6 proven; bf16 y2) =====
// blocks [0,NG): graph pooling ; [NG, NG+782): y2 = xb2 @ Wl2
__global__ __launch_bounds__(256)
void post_k(const u16* __restrict__ xb2, const int* __restrict__ cluster,
            float* __restrict__ g, const u16* __restrict__ WlT2,
            u16* __restrict__ yb) {
  __shared__ u16 wsh[64 * 128];         // 16 KB
  int tid = threadIdx.x;
  if (blockIdx.x < NG) {
    float* sh = (float*)wsh;
    int gid = blockIdx.x;
    int ch = tid & 127;
    int half = tid >> 7;
    int lo = 0, hi = NN;
    while (lo < hi) { int mid = (lo + hi) >> 1; if (cluster[mid] < gid) lo = mid + 1; else hi = mid; }
    int beg = lo;
    hi = NN;
    while (lo < hi) { int mid = (lo + hi) >> 1; if (cluster[mid] < gid + 1) lo = mid + 1; else hi = mid; }
    int end = lo;
    float s0 = 0.f, s1 = 0.f;
    int n = beg + half;
    for (; n + 2 < end; n += 4) {
      s0 += bf2f(xb2[(size_t)n * 128 + ch]);
      s1 += bf2f(xb2[(size_t)(n + 2) * 128 + ch]);
    }
    if (n < end) s0 += bf2f(xb2[(size_t)n * 128 + ch]);
    sh[tid] = s0 + s1;
    __syncthreads();
    if (tid < 128) {
      float s = sh[tid] + sh[tid + 128];
      g[gid * 128 + tid] = s / fmaxf((float)(end - beg), 1.0f);
    }
    return;
  }
  int bid = blockIdx.x - NG;
  {
    const u32x4* gw = (const u32x4*)WlT2;
    u32x4* l = (u32x4*)wsh;
#pragma unroll
    for (int i = 0; i < 4; i++)
      l[tid + i * 256] = gw[tid + i * 256];
  }
  __syncthreads();

  int wave = tid >> 6;
  int lane = tid & 63;
  int quad = lane >> 4;
  int m16  = lane & 15;
  int r0 = bid * 64 + wave * 16;

  int rowA = min(r0 + m16, NN - 1);
  const u16* px = xb2 + (size_t)rowA * 128 + quad * 8;
  bf16x8 a[4];
#pragma unroll
  for (int j = 0; j < 4; j++) a[j] = *(const bf16x8*)(px + j * 32);

  f32x4 acc[4];
#pragma unroll
  for (int nt = 0; nt < 4; nt++) acc[nt] = (f32x4){0.f, 0.f, 0.f, 0.f};

  int swz = m16 & 7;
#pragma unroll
  for (int ks = 0; ks < 4; ks++) {
#pragma unroll
    for (int nt = 0; nt < 4; nt++) {
      const u16* bp = wsh + (nt * 16 + m16) * 128 + (((ks * 4 + quad) ^ swz) << 3);
      bf16x8 b = *(const bf16x8*)bp;
      acc[nt] = __builtin_amdgcn_mfma_f32_16x16x32_bf16(a[ks], b, acc[nt], 0, 0, 0);
    }
  }

  int rbase = r0 + quad * 4;
#pragma unroll
  for (int r = 0; r < 4; r++) {
    int row = rbase + r;
    if (row < NN) {
#pragma unroll
      for (int nt = 0; nt < 4; nt++)
        yb[(size_t)row * 64 + nt * 16 + m16] = f2bf(acc[nt][r]);
    }
  }
}

// ===== final layer: out = log_softmax(aggY + bl2 + xb2 @ Wr2) =====
__global__ __launch_bounds__(256)
void sage64f_k(const u16* __restrict__ aggy, const u16* __restrict__ xbin,
               const u16* __restrict__ WT, const float* __restrict__ bl,
               float* __restrict__ out) {
  __shared__ u16 wsh[64 * 128];         // 16 KB
  int tid = threadIdx.x;
  {
    const u32x4* g = (const u32x4*)WT;
    u32x4* l = (u32x4*)wsh;
#pragma unroll
    for (int i = 0; i < 4; i++)
      l[tid + i * 256] = g[tid + i * 256];
  }
  __syncthreads();

  int wave = tid >> 6;
  int lane = tid & 63;
  int quad = lane >> 4;
  int m16  = lane & 15;
  int r0 = blockIdx.x * 64 + wave * 16;

  int rowA = min(r0 + m16, NN - 1);
  const u16* px = xbin + (size_t)rowA * 128 + quad * 8;
  bf16x8 a[4];
#pragma unroll
  for (int j = 0; j < 4; j++) a[j] = *(const bf16x8*)(px + j * 32);

  f32x4 acc[4];
#pragma unroll
  for (int nt = 0; nt < 4; nt++) acc[nt] = (f32x4){0.f, 0.f, 0.f, 0.f};

  int swz = m16 & 7;
#pragma unroll
  for (int ks = 0; ks < 4; ks++) {
#pragma unroll
    for (int nt = 0; nt < 4; nt++) {
      const u16* bp = wsh + (nt * 16 + m16) * 128 + (((ks * 4 + quad) ^ swz) << 3);
      bf16x8 b = *(const bf16x8*)bp;
      acc[nt] = __builtin_amdgcn_mfma_f32_16x16x32_bf16(a[ks], b, acc[nt], 0, 0, 0);
    }
  }

  float bv[4];
#pragma unroll
  for (int nt = 0; nt < 4; nt++) bv[nt] = bl[nt * 16 + m16];

  int rbase = r0 + quad * 4;
#pragma unroll
  for (int r = 0; r < 4; r++) {
    int row = rbase + r;
    int rs = min(row, NN - 1);
    float v0 = acc[0][r] + bv[0] + bf2f(aggy[(size_t)rs * 64 + m16]);
    float v1 = acc[1][r] + bv[1] + bf2f(aggy[(size_t)rs * 64 + 16 + m16]);
    float v2 = acc[2][r] + bv[2] + bf2f(aggy[(size_t)rs * 64 + 32 + m16]);
    float v3 = acc[3][r] + bv[3] + bf2f(aggy[(size_t)rs * 64 + 48 + m16]);
    float m = fmaxf(fmaxf(v0, v1), fmaxf(v2, v3));
#pragma unroll
    for (int mk = 1; mk <= 8; mk <<= 1) m = fmaxf(m, __shfl_xor(m, mk));
    float s = __expf(v0 - m) + __expf(v1 - m) + __expf(v2 - m) + __expf(v3 - m);
#pragma unroll
    for (int mk = 1; mk <= 8; mk <<= 1) s += __shfl_xor(s, mk);
    float ls = m + __logf(s);
    if (row < NN) {
      float* orow = out + (size_t)row * 64;
      orow[m16]      = v0 - ls;
      orow[16 + m16] = v1 - ls;
      orow[32 + m16] = v2 - ls;
      orow[48 + m16] = v3 - ls;
    }
  }
}

extern "C" void kernel_launch(void* const* d_in, const int* in_sizes, int n_in,
                              void* d_out, int out_size, void* d_ws, size_t ws_size,
                              hipStream_t stream) {
  const float* x   = (const float*)d_in[0];
  const int*   ei  = (const int*)d_in[1];
  const int*   cl  = (const int*)d_in[2];
  const float* Wl0 = (const float*)d_in[3];
  const float* bl0 = (const float*)d_in[4];
  const float* Wr0 = (const float*)d_in[5];
  const float* Wl1 = (const float*)d_in[6];
  const float* bl1 = (const float*)d_in[7];
  const float* Wr1 = (const float*)d_in[8];
  const float* Wl2 = (const float*)d_in[9];
  const float* bl2 = (const float*)d_in[10];
  const float* Wr2 = (const float*)d_in[11];
  float* out = (float*)d_out;

  char* ws = (char*)d_ws;
  u16*   xb0     = (u16*)  (ws);                  // 12,800,000 B (bf16 of x)
  u16*   xb1     = (u16*)  (ws + 12800000);       // 12,800,000 B (relu layer0)
  u16*   xb2     = (u16*)  (ws + 25600000);       // 12,800,000 B (relu layer1)
  // xq (fp8 gather table, 6.4 MB) aliases xb2's first half: written by prep (fp8 x)
  // and sage-L0 (fp8 relu0); last READ by the L1 gather, then xb2 overwrites it.
  u8*    xq      = (u8*)   (ws + 25600000);
  u16*   aggb    = (u16*)  (ws + 38400000);       // 12,800,000 B (L0/L1 agg)
  u16*   y2      = aggb;                          //  6,400,000 B (xb2 @ Wl2, bf16)
  u16*   aggy    = (u16*)  (ws + 44800000);       //  6,400,000 B
  u16*   WbT0    = (u16*)  (ws + 51200000);       //     65,536 B (swizzled, K=256)
  u16*   WbT1    = (u16*)  (ws + 51265536);       //     65,536 B
  u16*   WlT2    = (u16*)  (ws + 51331072);       //     16,384 B (swizzled, K=128)
  u16*   WrT2    = (u16*)  (ws + 51347456);       //     16,384 B
  int*   deg     = (int*)  (ws + 51363840);       //    200,000 B
  int*   row_ptr = (int*)  (ws + 51564032);       //    200,004 B (+pad)
  int*   cursor  = (int*)  (ws + 51764736);       //    200,000 B
  int*   perm    = (int*)  (ws + 51964736);       //  2,400,000 B
  int*   bsum    = (int*)  (ws + 54364736);       //        784 B
  int*   bofs    = (int*)  (ws + 54365568);       //        784 B
  // total ~54.4 MB

  float* out_lsm = out;            // [50000,64]
  float* out_pre = out + 3200000;  // [50000,128]
  float* out_g   = out + 9600000;  // [512,128]

  // ---- fused prep (cast x bf16+fp8, deg count, all weight casts) ----
  hipMemsetAsync(deg, 0, 200000, stream);
  prep_k<<<15164, 256, 0, stream>>>(x, (u32*)xb0, (u16*)xq, ei, deg,
                                    Wl0, Wr0, WbT0, Wl1, Wr1, WbT1,
                                    Wl2, WlT2, Wr2, WrT2);

  // ---- CSR scans + fill ----
  scan1_k<<<196, 256, 0, stream>>>(deg, bsum);
  scan2_k<<<1, 256, 0, stream>>>(bsum, bofs, row_ptr);
  scan3_k<<<196, 256, 0, stream>>>(deg, bofs, row_ptr, cursor);
  fill_k<<<2344, 256, 0, stream>>>(ei, cursor, perm);

  // ---- layer 0: fp8 gather @ full concurrency + MFMA (epilogue writes fp8 relu0) ----
  gatherq12_k<<<3125, 256, 0, stream>>>(xq, row_ptr, perm, aggb);
  sage_mfma_v2_k<false, true><<<782, 256, 0, stream>>>(aggb, xb0, WbT0, bl0, xb1, nullptr, xq);

  // ---- layer 1: fp8 gather + MFMA (pre-relu f32 straight to d_out) ----
  gatherq12_k<<<3125, 256, 0, stream>>>(xq, row_ptr, perm, aggb);
  sage_mfma_v2_k<true, false><<<782, 256, 0, stream>>>(aggb, xb1, WbT1, bl1, xb2, out_pre, nullptr);

  // ---- pooling + y2 GEMM (merged, both read xb2) ----
  post_k<<<NG + 782, 256, 0, stream>>>(xb2, cl, out_g, WlT2, y2);

  // ---- final layer via linearity: aggY = gather-mean(y2, 128B rows);
  //      out = log_softmax(aggY + bl2 + xb2@Wr2) ----
  gather8_k<<<1563, 256, 0, stream>>>(y2, row_ptr, perm, aggy);
  sage64f_k<<<782, 256, 0, stream>>>(aggy, xb2, WrT2, bl2, out_lsm);
}

// Round 12
// 282.552 us; speedup vs baseline: 1.8819x; 1.1060x over previous
//
#include <hip/hip_runtime.h>
#include <math.h>

#define NN 50000
#define NE 600000
#define NG 512

typedef unsigned int u32;
typedef unsigned short u16;

typedef __attribute__((ext_vector_type(8))) short bf16x8;
typedef __attribute__((ext_vector_type(4))) float f32x4;
typedef __attribute__((ext_vector_type(4))) unsigned int u32x4;

__device__ __forceinline__ float bf2f(u16 u) {
  return __uint_as_float(((u32)u) << 16);
}
__device__ __forceinline__ u16 f2bf(float f) {
  u32 u = __float_as_uint(f);
  u32 lsb = (u >> 16) & 1u;
  u += 0x7fffu + lsb;          // RNE
  return (u16)(u >> 16);
}

// ================= fused prep: cast x, count degrees, cast+transpose weights ========
// blocks [0,12500): cast x->xb ; [12500,14844): deg_count ;
// [14844,14972): castW0 (swz) ; [14972,15100): castW1 (swz) ;
// [15100,15132): WlT2 (swz) ; [15132,15164): WrT2 (swz)
__global__ __launch_bounds__(256)
void prep_k(const float* __restrict__ x, u32* __restrict__ xb,
            const int* __restrict__ ei, int* __restrict__ deg,
            const float* __restrict__ Wl0, const float* __restrict__ Wr0, u16* __restrict__ WbT0,
            const float* __restrict__ Wl1, const float* __restrict__ Wr1, u16* __restrict__ WbT1,
            const float* __restrict__ Wl2, u16* __restrict__ WlT2,
            const float* __restrict__ Wr2, u16* __restrict__ WrT2) {
  int b = blockIdx.x;
  int tid = threadIdx.x;
  if (b < 12500) {
    int t = b * 256 + tid;                       // 3,200,000 exactly
    float2 v = ((const float2*)x)[t];
    xb[t] = (u32)f2bf(v.x) | ((u32)f2bf(v.y) << 16);
  } else if (b < 14844) {
    int e = (b - 12500) * 256 + tid;
    if (e < NE) atomicAdd(&deg[ei[NE + e]], 1);
  } else if (b < 15100) {
    // K=256 weight cast+transpose, pre-swizzled: WbT[n][k], 16B chunk idx ^= (n&7)
    bool w1 = (b >= 14972);
    int t = (b - (w1 ? 14972 : 14844)) * 256 + tid;   // 128*256
    int n = t >> 8;
    int k = t & 255;
    const float* Wl = w1 ? Wl1 : Wl0;
    const float* Wr = w1 ? Wr1 : Wr0;
    float v = (k < 128) ? Wl[k * 128 + n] : Wr[(k - 128) * 128 + n];
    int c = k >> 3, e = k & 7;
    u16* dst = w1 ? WbT1 : WbT0;
    dst[n * 256 + (((c ^ (n & 7)) << 3) | e)] = f2bf(v);
  } else {
    // K=128 -> 64 cols, pre-swizzled
    bool wr = (b >= 15132);
    int t = (b - (wr ? 15132 : 15100)) * 256 + tid;   // 8192 = 64*128
    int n = t >> 7;
    int k = t & 127;
    const float* W = wr ? Wr2 : Wl2;
    float v = W[k * 64 + n];
    int c = k >> 3, e = k & 7;
    u16* dst = wr ? WrT2 : WlT2;
    dst[n * 128 + (((c ^ (n & 7)) << 3) | e)] = f2bf(v);
  }
}

// ================= CSR scans ========
__global__ __launch_bounds__(256)
void scan1_k(const int* __restrict__ deg, int* __restrict__ bsum) {
  __shared__ int s[256];
  int idx = blockIdx.x * 256 + threadIdx.x;
  int v = (idx < NN) ? deg[idx] : 0;
  s[threadIdx.x] = v;
  __syncthreads();
  for (int off = 128; off > 0; off >>= 1) {
    if (threadIdx.x < off) s[threadIdx.x] += s[threadIdx.x + off];
    __syncthreads();
  }
  if (threadIdx.x == 0) bsum[blockIdx.x] = s[0];
}

__global__ __launch_bounds__(256)
void scan2_k(const int* __restrict__ bsum, int* __restrict__ bofs, int* __restrict__ row_ptr) {
  __shared__ int s[256];
  int t = threadIdx.x;
  int v = (t < 196) ? bsum[t] : 0;
  s[t] = v;
  __syncthreads();
  for (int off = 1; off < 256; off <<= 1) {
    int add = (t >= off) ? s[t - off] : 0;
    __syncthreads();
    s[t] += add;
    __syncthreads();
  }
  if (t < 196) bofs[t] = s[t] - v;     // exclusive
  if (t == 0) row_ptr[NN] = NE;
}

__global__ __launch_bounds__(256)
void scan3_k(const int* __restrict__ deg, const int* __restrict__ bofs,
             int* __restrict__ row_ptr, int* __restrict__ cursor) {
  __shared__ int s[256];
  int idx = blockIdx.x * 256 + threadIdx.x;
  int t = threadIdx.x;
  int v = (idx < NN) ? deg[idx] : 0;
  s[t] = v;
  __syncthreads();
  for (int off = 1; off < 256; off <<= 1) {
    int add = (t >= off) ? s[t - off] : 0;
    __syncthreads();
    s[t] += add;
    __syncthreads();
  }
  if (idx < NN) {
    int p = bofs[blockIdx.x] + s[t] - v;
    row_ptr[idx] = p;
    cursor[idx] = p;
  }
}

__global__ __launch_bounds__(256)
void fill_k(const int* __restrict__ ei, int* __restrict__ cursor, int* __restrict__ perm) {
  int e = blockIdx.x * 256 + threadIdx.x;
  if (e >= NE) return;
  int pos = atomicAdd(&cursor[ei[NE + e]], 1);
  perm[pos] = ei[e];
}

// ===== gather-mean (128 ch): 4 nodes/wave, batch-8 dwordx4 (8 KB in flight) =====
// group = lane>>4 owns node; lane16 owns 16 B of the 256 B row.
__global__ __launch_bounds__(256)
void gather4_k(const u16* __restrict__ xb, const int* __restrict__ row_ptr,
               const int* __restrict__ perm, u16* __restrict__ aggb) {
  int wave = threadIdx.x >> 6;
  int lane = threadIdx.x & 63;
  int grp  = lane >> 4;
  int l16  = lane & 15;
  int n = (blockIdx.x * 4 + wave) * 4 + grp;     // 3125*4*4 = 50000
  int beg = row_ptr[n];
  int cnt = row_ptr[n + 1] - beg;
  int beg_s = min(beg, NE - 1);                  // safe base for clamped reads
  int last = max(cnt - 1, 0);
  int m = max(cnt, __shfl_xor(cnt, 16));
  int jmax = max(m, __shfl_xor(m, 32));          // wave-uniform loop bound
  float acc[8];
#pragma unroll
  for (int i = 0; i < 8; i++) acc[i] = 0.f;
  const u32x4* xv = (const u32x4*)xb;            // row = 16 chunks of 16 B
  for (int base = 0; base < jmax; base += 8) {
    int idx[8];
#pragma unroll
    for (int j = 0; j < 8; j++) idx[j] = perm[beg_s + min(base + j, last)];
    u32x4 v[8];
#pragma unroll
    for (int j = 0; j < 8; j++) v[j] = xv[(size_t)idx[j] * 16 + l16];
#pragma unroll
    for (int j = 0; j < 8; j++) {
      bool live = (base + j) < cnt;
#pragma unroll
      for (int w = 0; w < 4; w++) {
        u32 u = v[j][w];
        acc[2 * w]     += live ? __uint_as_float(u << 16) : 0.f;
        acc[2 * w + 1] += live ? __uint_as_float(u & 0xffff0000u) : 0.f;
      }
    }
  }
  float inv = 1.0f / fmaxf((float)cnt, 1.0f);
  u32x4 o;
#pragma unroll
  for (int w = 0; w < 4; w++)
    o[w] = (u32)f2bf(acc[2 * w] * inv) | ((u32)f2bf(acc[2 * w + 1] * inv) << 16);
  ((u32x4*)aggb)[(size_t)n * 16 + l16] = o;
}

// ===== gather-mean (64 ch rows = 128 B = ONE cache line/edge): 8 nodes/wave, batch-8 =====
// group = lane>>3 owns node; lane8 owns 16 B of the 128 B row.
__global__ __launch_bounds__(256)
void gather8_k(const u16* __restrict__ yb, const int* __restrict__ row_ptr,
               const int* __restrict__ perm, u16* __restrict__ aggy) {
  int wave = threadIdx.x >> 6;
  int lane = threadIdx.x & 63;
  int grp  = lane >> 3;               // 0..7
  int li   = lane & 7;
  int n = (blockIdx.x * 4 + wave) * 8 + grp;     // 1563*4*8 = 50016 (tail clamped)
  int ns = min(n, NN - 1);
  int beg = row_ptr[ns];
  int cnt = row_ptr[ns + 1] - beg;
  int beg_s = min(beg, NE - 1);
  int last = max(cnt - 1, 0);
  int m = max(cnt, __shfl_xor(cnt, 8));
  m = max(m, __shfl_xor(m, 16));
  int jmax = max(m, __shfl_xor(m, 32));          // wave-uniform loop bound
  float acc[8];
#pragma unroll
  for (int i = 0; i < 8; i++) acc[i] = 0.f;
  const u32x4* xv = (const u32x4*)yb;            // row = 8 chunks of 16 B
  for (int base = 0; base < jmax; base += 8) {
    int idx[8];
#pragma unroll
    for (int j = 0; j < 8; j++) idx[j] = perm[beg_s + min(base + j, last)];
    u32x4 v[8];
#pragma unroll
    for (int j = 0; j < 8; j++) v[j] = xv[(size_t)idx[j] * 8 + li];
#pragma unroll
    for (int j = 0; j < 8; j++) {
      bool live = (base + j) < cnt;
#pragma unroll
      for (int w = 0; w < 4; w++) {
        u32 u = v[j][w];
        acc[2 * w]     += live ? __uint_as_float(u << 16) : 0.f;
        acc[2 * w + 1] += live ? __uint_as_float(u & 0xffff0000u) : 0.f;
      }
    }
  }
  float inv = 1.0f / fmaxf((float)cnt, 1.0f);
  u32x4 o;
#pragma unroll
  for (int w = 0; w < 4; w++)
    o[w] = (u32)f2bf(acc[2 * w] * inv) | ((u32)f2bf(acc[2 * w + 1] * inv) << 16);
  if (n < NN) ((u32x4*)aggy)[(size_t)n * 8 + li] = o;
}

// ===== MFMA SAGE layer (Cout=128): block = 64 rows x 128 cols, W (K=256) in LDS =====
template<bool WRITE_PRE>
__global__ __launch_bounds__(256)
void sage_mfma_v2_k(const u16* __restrict__ aggb, const u16* __restrict__ xbin,
                    const u16* __restrict__ WbT, const float* __restrict__ bl,
                    u16* __restrict__ xb_out, float* __restrict__ out_pre) {
  __shared__ u16 wsh[128 * 256];        // 64 KB
  int tid = threadIdx.x;
  {
    const u32x4* g = (const u32x4*)WbT;
    u32x4* l = (u32x4*)wsh;
#pragma unroll
    for (int i = 0; i < 16; i++)
      l[tid + i * 256] = g[tid + i * 256];
  }
  __syncthreads();

  int wave = tid >> 6;
  int lane = tid & 63;
  int quad = lane >> 4;
  int m16  = lane & 15;
  int r0 = blockIdx.x * 64 + wave * 16;

  int rowA = min(r0 + m16, NN - 1);
  const u16* pa = aggb + (size_t)rowA * 128 + quad * 8;
  const u16* px = xbin + (size_t)rowA * 128 + quad * 8;
  bf16x8 a[8];
#pragma unroll
  for (int j = 0; j < 4; j++) a[j]     = *(const bf16x8*)(pa + j * 32);
#pragma unroll
  for (int j = 0; j < 4; j++) a[4 + j] = *(const bf16x8*)(px + j * 32);

  f32x4 acc[8];
#pragma unroll
  for (int nt = 0; nt < 8; nt++) acc[nt] = (f32x4){0.f, 0.f, 0.f, 0.f};

  int swz = m16 & 7;
#pragma unroll
  for (int ks = 0; ks < 8; ks++) {
#pragma unroll
    for (int nt = 0; nt < 8; nt++) {
      const u16* bp = wsh + (nt * 16 + m16) * 256 + (((quad + ks * 4) ^ swz) << 3);
      bf16x8 b = *(const bf16x8*)bp;
      acc[nt] = __builtin_amdgcn_mfma_f32_16x16x32_bf16(a[ks], b, acc[nt], 0, 0, 0);
    }
  }

  float bv[8];
#pragma unroll
  for (int nt = 0; nt < 8; nt++) bv[nt] = bl[nt * 16 + m16];

  int rbase = r0 + quad * 4;
#pragma unroll
  for (int r = 0; r < 4; r++) {
    int row = rbase + r;
    if (row < NN) {
#pragma unroll
      for (int nt = 0; nt < 8; nt++) {
        int col = nt * 16 + m16;
        float v = acc[nt][r] + bv[nt];
        if (WRITE_PRE) out_pre[(size_t)row * 128 + col] = v;
        xb_out[(size_t)row * 128 + col] = f2bf(fmaxf(v, 0.f));
      }
    }
  }
}

// ===== pre-GEMM for final layer: y2 = xb2 @ Wl2 (K=128 -> 64 cols, bf16 out) =====
__global__ __launch_bounds__(256)
void gemm64_k(const u16* __restrict__ xbin, const u16* __restrict__ WT,
              u16* __restrict__ yb) {
  __shared__ u16 wsh[64 * 128];         // 16 KB
  int tid = threadIdx.x;
  {
    const u32x4* g = (const u32x4*)WT;
    u32x4* l = (u32x4*)wsh;
#pragma unroll
    for (int i = 0; i < 4; i++)
      l[tid + i * 256] = g[tid + i * 256];
  }
  __syncthreads();

  int wave = tid >> 6;
  int lane = tid & 63;
  int quad = lane >> 4;
  int m16  = lane & 15;
  int r0 = blockIdx.x * 64 + wave * 16;

  int rowA = min(r0 + m16, NN - 1);
  const u16* px = xbin + (size_t)rowA * 128 + quad * 8;
  bf16x8 a[4];
#pragma unroll
  for (int j = 0; j < 4; j++) a[j] = *(const bf16x8*)(px + j * 32);

  f32x4 acc[4];
#pragma unroll
  for (int nt = 0; nt < 4; nt++) acc[nt] = (f32x4){0.f, 0.f, 0.f, 0.f};

  int swz = m16 & 7;
#pragma unroll
  for (int ks = 0; ks < 4; ks++) {
#pragma unroll
    for (int nt = 0; nt < 4; nt++) {
      const u16* bp = wsh + (nt * 16 + m16) * 128 + (((ks * 4 + quad) ^ swz) << 3);
      bf16x8 b = *(const bf16x8*)bp;
      acc[nt] = __builtin_amdgcn_mfma_f32_16x16x32_bf16(a[ks], b, acc[nt], 0, 0, 0);
    }
  }

  int rbase = r0 + quad * 4;
#pragma unroll
  for (int r = 0; r < 4; r++) {
    int row = rbase + r;
    if (row < NN) {
#pragma unroll
      for (int nt = 0; nt < 4; nt++)
        yb[(size_t)row * 64 + nt * 16 + m16] = f2bf(acc[nt][r]);
    }
  }
}

// ===== final layer: out = log_softmax(aggY + bl2 + xb2 @ Wr2) =====
__global__ __launch_bounds__(256)
void sage64f_k(const u16* __restrict__ aggy, const u16* __restrict__ xbin,
               const u16* __restrict__ WT, const float* __restrict__ bl,
               float* __restrict__ out) {
  __shared__ u16 wsh[64 * 128];         // 16 KB
  int tid = threadIdx.x;
  {
    const u32x4* g = (const u32x4*)WT;
    u32x4* l = (u32x4*)wsh;
#pragma unroll
    for (int i = 0; i < 4; i++)
      l[tid + i * 256] = g[tid + i * 256];
  }
  __syncthreads();

  int wave = tid >> 6;
  int lane = tid & 63;
  int quad = lane >> 4;
  int m16  = lane & 15;
  int r0 = blockIdx.x * 64 + wave * 16;

  int rowA = min(r0 + m16, NN - 1);
  const u16* px = xbin + (size_t)rowA * 128 + quad * 8;
  bf16x8 a[4];
#pragma unroll
  for (int j = 0; j < 4; j++) a[j] = *(const bf16x8*)(px + j * 32);

  f32x4 acc[4];
#pragma unroll
  for (int nt = 0; nt < 4; nt++) acc[nt] = (f32x4){0.f, 0.f, 0.f, 0.f};

  int swz = m16 & 7;
#pragma unroll
  for (int ks = 0; ks < 4; ks++) {
#pragma unroll
    for (int nt = 0; nt < 4; nt++) {
      const u16* bp = wsh + (nt * 16 + m16) * 128 + (((ks * 4 + quad) ^ swz) << 3);
      bf16x8 b = *(const bf16x8*)bp;
      acc[nt] = __builtin_amdgcn_mfma_f32_16x16x32_bf16(a[ks], b, acc[nt], 0, 0, 0);
    }
  }

  float bv[4];
#pragma unroll
  for (int nt = 0; nt < 4; nt++) bv[nt] = bl[nt * 16 + m16];

  int rbase = r0 + quad * 4;
#pragma unroll
  for (int r = 0; r < 4; r++) {
    int row = rbase + r;
    int rs = min(row, NN - 1);
    float v0 = acc[0][r] + bv[0] + bf2f(aggy[(size_t)rs * 64 + m16]);
    float v1 = acc[1][r] + bv[1] + bf2f(aggy[(size_t)rs * 64 + 16 + m16]);
    float v2 = acc[2][r] + bv[2] + bf2f(aggy[(size_t)rs * 64 + 32 + m16]);
    float v3 = acc[3][r] + bv[3] + bf2f(aggy[(size_t)rs * 64 + 48 + m16]);
    float m = fmaxf(fmaxf(v0, v1), fmaxf(v2, v3));
#pragma unroll
    for (int mk = 1; mk <= 8; mk <<= 1) m = fmaxf(m, __shfl_xor(m, mk));
    float s = __expf(v0 - m) + __expf(v1 - m) + __expf(v2 - m) + __expf(v3 - m);
#pragma unroll
    for (int mk = 1; mk <= 8; mk <<= 1) s += __shfl_xor(s, mk);
    float ls = m + __logf(s);
    if (row < NN) {
      float* orow = out + (size_t)row * 64;
      orow[m16]      = v0 - ls;
      orow[16 + m16] = v1 - ls;
      orow[32 + m16] = v2 - ls;
      orow[48 + m16] = v3 - ls;
    }
  }
}

// ======= graph pooling: 256 thr/block, odd/even node split + LDS combine =======
__global__ __launch_bounds__(256)
void pool_seg_k(const u16* __restrict__ xb, const int* __restrict__ cluster,
                float* __restrict__ g) {
  __shared__ float sh[256];
  int gid = blockIdx.x;          // 512
  int t = threadIdx.x;
  int ch = t & 127;
  int half = t >> 7;
  int lo = 0, hi = NN;
  while (lo < hi) { int mid = (lo + hi) >> 1; if (cluster[mid] < gid) lo = mid + 1; else hi = mid; }
  int beg = lo;
  hi = NN;
  while (lo < hi) { int mid = (lo + hi) >> 1; if (cluster[mid] < gid + 1) lo = mid + 1; else hi = mid; }
  int end = lo;
  float s0 = 0.f, s1 = 0.f;
  int n = beg + half;
  for (; n + 2 < end; n += 4) {
    s0 += bf2f(xb[(size_t)n * 128 + ch]);
    s1 += bf2f(xb[(size_t)(n + 2) * 128 + ch]);
  }
  if (n < end) s0 += bf2f(xb[(size_t)n * 128 + ch]);
  sh[t] = s0 + s1;
  __syncthreads();
  if (t < 128) {
    float s = sh[t] + sh[t + 128];
    g[gid * 128 + t] = s / fmaxf((float)(end - beg), 1.0f);
  }
}

extern "C" void kernel_launch(void* const* d_in, const int* in_sizes, int n_in,
                              void* d_out, int out_size, void* d_ws, size_t ws_size,
                              hipStream_t stream) {
  const float* x   = (const float*)d_in[0];
  const int*   ei  = (const int*)d_in[1];
  const int*   cl  = (const int*)d_in[2];
  const float* Wl0 = (const float*)d_in[3];
  const float* bl0 = (const float*)d_in[4];
  const float* Wr0 = (const float*)d_in[5];
  const float* Wl1 = (const float*)d_in[6];
  const float* bl1 = (const float*)d_in[7];
  const float* Wr1 = (const float*)d_in[8];
  const float* Wl2 = (const float*)d_in[9];
  const float* bl2 = (const float*)d_in[10];
  const float* Wr2 = (const float*)d_in[11];
  float* out = (float*)d_out;

  char* ws = (char*)d_ws;
  u16*   xb0     = (u16*)  (ws);                  // 12,800,000 B (bf16 of x)
  u16*   xb1     = (u16*)  (ws + 12800000);       // 12,800,000 B (relu layer0)
  u16*   xb2     = (u16*)  (ws + 25600000);       // 12,800,000 B (relu layer1)
  u16*   y2      = (u16*)  (ws + 38400000);       //  6,400,000 B (xb2 @ Wl2, bf16)
  u16*   aggy    = (u16*)  (ws + 44800000);       //  6,400,000 B
  u16*   aggb    = (u16*)  (ws + 38400000);       // 12,800,000 B (L0/L1 agg; aliases y2+aggy)
  u16*   WbT0    = (u16*)  (ws + 51200000);       //     65,536 B (swizzled, K=256)
  u16*   WbT1    = (u16*)  (ws + 51265536);       //     65,536 B
  u16*   WlT2    = (u16*)  (ws + 51331072);       //     16,384 B (swizzled, K=128)
  u16*   WrT2    = (u16*)  (ws + 51347456);       //     16,384 B
  int*   deg     = (int*)  (ws + 51363840);       //    200,000 B
  int*   row_ptr = (int*)  (ws + 51564032);       //    200,004 B (+pad)
  int*   cursor  = (int*)  (ws + 51764736);       //    200,000 B
  int*   perm    = (int*)  (ws + 51964736);       //  2,400,000 B
  int*   bsum    = (int*)  (ws + 54364736);       //        784 B
  int*   bofs    = (int*)  (ws + 54365568);       //        784 B
  // total ~54.4 MB

  float* out_lsm = out;            // [50000,64]
  float* out_pre = out + 3200000;  // [50000,128]
  float* out_g   = out + 9600000;  // [512,128]

  // ---- fused prep (cast x, deg count, all weight casts) ----
  hipMemsetAsync(deg, 0, 200000, stream);
  prep_k<<<15164, 256, 0, stream>>>(x, (u32*)xb0, ei, deg,
                                    Wl0, Wr0, WbT0, Wl1, Wr1, WbT1,
                                    Wl2, WlT2, Wr2, WrT2);

  // ---- CSR scans + fill ----
  scan1_k<<<196, 256, 0, stream>>>(deg, bsum);
  scan2_k<<<1, 256, 0, stream>>>(bsum, bofs, row_ptr);
  scan3_k<<<196, 256, 0, stream>>>(deg, bofs, row_ptr, cursor);
  fill_k<<<2344, 256, 0, stream>>>(ei, cursor, perm);

  // ---- layer 0 ----
  gather4_k<<<3125, 256, 0, stream>>>(xb0, row_ptr, perm, aggb);
  sage_mfma_v2_k<false><<<782, 256, 0, stream>>>(aggb, xb0, WbT0, bl0, xb1, nullptr);

  // ---- layer 1 (pre-relu f32 straight to d_out) ----
  gather4_k<<<3125, 256, 0, stream>>>(xb1, row_ptr, perm, aggb);
  sage_mfma_v2_k<true><<<782, 256, 0, stream>>>(aggb, xb1, WbT1, bl1, xb2, out_pre);

  // ---- graph pooling of relu(layer1) ----
  pool_seg_k<<<NG, 256, 0, stream>>>(xb2, cl, out_g);

  // ---- final layer via linearity: y2 = xb2@Wl2; aggY = gather-mean(y2);
  //      out = log_softmax(aggY + bl2 + xb2@Wr2) ----
  gemm64_k<<<782, 256, 0, stream>>>(xb2, WlT2, y2);
  gather8_k<<<1563, 256, 0, stream>>>(y2, row_ptr, perm, aggy);
  sage64f_k<<<782, 256, 0, stream>>>(aggy, xb2, WrT2, bl2, out_lsm);
}